// Round 5
// baseline (1427.509 us; speedup 1.0000x reference)
//
#include <hip/hip_runtime.h>

#define NREL 8
#define CH   128                 // IN_CH == HID == 128
#define KTOT 1152                // 8*128 (relations) + 128 (root)

#define SCAN_ITEMS   16
#define SCAN_THREADS 256
#define SCAN_CHUNK   (SCAN_ITEMS * SCAN_THREADS)   // 4096
#define SCAN_SHIFT   12

#define BM   64                  // nodes per fused block
#define APAD 140                 // As32 row stride (dwords): 560 B, 16B-aligned, 2-way banks

typedef short  short8v __attribute__((ext_vector_type(8)));
typedef float  f32x4   __attribute__((ext_vector_type(4)));

__device__ __forceinline__ unsigned short f2bf(float f) {
    union { float f; unsigned u; } v; v.f = f;
    return (unsigned short)((v.u + 0x7FFFu + ((v.u >> 16) & 1u)) >> 16);
}
__device__ __forceinline__ void gload_lds16(const void* g, void* l) {
    __builtin_amdgcn_global_load_lds(
        (const __attribute__((address_space(1))) unsigned int*)g,
        (__attribute__((address_space(3))) unsigned int*)l, 16, 0, 0);
}

// ---------------------------------------------------------------------------
// 0a. x fp32 -> bf16
// ---------------------------------------------------------------------------
__global__ __launch_bounds__(256) void cvtx_kernel(
    const float* __restrict__ x, unsigned short* __restrict__ xb, int total4)
{
    int i = blockIdx.x * blockDim.x + threadIdx.x;
    if (i >= total4) return;
    float4 v = *(const float4*)(x + (size_t)i * 4);
    ushort4 o;
    o.x = f2bf(v.x); o.y = f2bf(v.y); o.z = f2bf(v.z); o.w = f2bf(v.w);
    *(ushort4*)(xb + (size_t)i * 4) = o;
}

// ---------------------------------------------------------------------------
// 0b. Bt[c][k] = bf16( k<1024 ? W[k][c] : root[k-1024][c] )
// ---------------------------------------------------------------------------
__global__ __launch_bounds__(256) void bt_kernel(
    const float* __restrict__ W, const float* __restrict__ root,
    unsigned short* __restrict__ Bt)
{
    int idx = blockIdx.x * blockDim.x + threadIdx.x;   // c*1152 + k
    if (idx >= CH * KTOT) return;
    int c = idx / KTOT, k = idx - c * KTOT;
    float v = (k < NREL * CH) ? W[(size_t)k * CH + c]
                              : root[(size_t)(k - NREL * CH) * CH + c];
    Bt[idx] = f2bf(v);
}

// ---------------------------------------------------------------------------
// 1. histogram, REL-MAJOR segments: seg = et*N + dst
// ---------------------------------------------------------------------------
__global__ __launch_bounds__(256) void hist_kernel(
    const int* __restrict__ dst, const int* __restrict__ et,
    int* __restrict__ hist, int E, int N)
{
    int stride = gridDim.x * blockDim.x;
    for (int e = blockIdx.x * blockDim.x + threadIdx.x; e < E; e += stride)
        atomicAdd(&hist[et[e] * N + dst[e]], 1);
}

// ---------------------------------------------------------------------------
// 2a/2b. two-level exclusive scan
// ---------------------------------------------------------------------------
__global__ __launch_bounds__(SCAN_THREADS) void scan1_kernel(
    const int* __restrict__ hist, int* __restrict__ offs,
    int* __restrict__ partials, int S)
{
    __shared__ int lds[SCAN_THREADS];
    int t = threadIdx.x;
    int base = blockIdx.x * SCAN_CHUNK + t * SCAN_ITEMS;
    int v[SCAN_ITEMS];
    int s = 0;
#pragma unroll
    for (int j = 0; j < SCAN_ITEMS; j++) {
        int idx = base + j;
        int h = (idx < S) ? hist[idx] : 0;
        v[j] = s; s += h;
    }
    int run = s;
    lds[t] = run; __syncthreads();
    for (int off = 1; off < SCAN_THREADS; off <<= 1) {
        int y = (t >= off) ? lds[t - off] : 0;
        __syncthreads();
        run += y; lds[t] = run; __syncthreads();
    }
    int tb = run - s;
    if (t == SCAN_THREADS - 1) partials[blockIdx.x] = run;
#pragma unroll
    for (int j = 0; j < SCAN_ITEMS; j++) {
        int idx = base + j;
        if (idx < S) offs[idx] = tb + v[j];
    }
}

__global__ __launch_bounds__(SCAN_THREADS) void scan2_kernel(
    int* __restrict__ partials, int NB)
{
    __shared__ int lds[SCAN_THREADS];
    int t = threadIdx.x;
    int s = (t < NB) ? partials[t] : 0;
    int run = s;
    lds[t] = run; __syncthreads();
    for (int off = 1; off < SCAN_THREADS; off <<= 1) {
        int y = (t >= off) ? lds[t - off] : 0;
        __syncthreads();
        run += y; lds[t] = run; __syncthreads();
    }
    if (t < NB) partials[t] = run - s;
}

// ---------------------------------------------------------------------------
// 2c. offs -> absolute (+sentinel); invcnt[i] = 1/max(hist[i],1)
// ---------------------------------------------------------------------------
__global__ __launch_bounds__(256) void finalize_kernel(
    int* __restrict__ offs, const int* __restrict__ partials,
    const int* __restrict__ hist, float* __restrict__ invcnt, int S, int E)
{
    int i = blockIdx.x * blockDim.x + threadIdx.x;
    if (i < S) {
        offs[i] += partials[i >> SCAN_SHIFT];
        invcnt[i] = 1.0f / (float)max(hist[i], 1);
    } else if (i == S) offs[i] = E;
}

// ---------------------------------------------------------------------------
// 3. fill permutation: perm[pos] = src | (dst&63)<<20  (rel-major segs)
// ---------------------------------------------------------------------------
__global__ __launch_bounds__(256) void fill_kernel(
    const int* __restrict__ src, const int* __restrict__ dst,
    const int* __restrict__ et, const int* __restrict__ offs,
    int* __restrict__ cursor, int* __restrict__ perm, int E, int N)
{
    int stride = gridDim.x * blockDim.x;
    for (int e = blockIdx.x * blockDim.x + threadIdx.x; e < E; e += stride) {
        int d = dst[e];
        int seg = et[e] * N + d;
        int pos = offs[seg] + atomicAdd(&cursor[seg], 1);
        perm[pos] = src[e] | ((d & (BM - 1)) << 20);
    }
}

// ---------------------------------------------------------------------------
// 4. FUSED aggregate + GEMM.
//    Per block: 64 output nodes x 128 hid. For each rel r: zero fp32 LDS
//    accumulator, stage Bs (swizzled), edge-parallel gather with pre-scaled
//    ds_add_f32, then 4 MFMA K-steps accumulating into acc. Rel 8 = root:
//    A-frags straight from global xb. Epilogue: bias + ReLU.
// ---------------------------------------------------------------------------
__global__ __launch_bounds__(512, 4) void fused_kernel(
    const unsigned short* __restrict__ xb,
    const unsigned short* __restrict__ Bt,   // [128][1152] bf16
    const int* __restrict__ perm,
    const int* __restrict__ offs,
    const float* __restrict__ invcnt,
    const float* __restrict__ bias,
    float* __restrict__ out, int N)
{
    __shared__ __align__(16) float As32[BM * APAD];            // 35840 B
    __shared__ __align__(16) unsigned short Bs[CH * CH];       // 32768 B

    int tid  = threadIdx.x;
    int lane = tid & 63;
    int wid  = tid >> 6;          // 0..7
    int wm   = wid >> 2;          // 0..1 -> rows wm*32
    int wn   = wid & 3;           // 0..3 -> cols wn*32
    int r15  = lane & 15;
    int kg   = lane >> 4;         // 0..3
    int n0   = blockIdx.x * BM;
    int nEnd = min(n0 + BM, N);

    f32x4 acc[2][2];
#pragma unroll
    for (int i = 0; i < 2; i++)
#pragma unroll
        for (int j = 0; j < 2; j++)
            acc[i][j] = f32x4{0.f, 0.f, 0.f, 0.f};

    for (int r = 0; r <= NREL; ++r) {
        if (r > 0) __syncthreads();   // prev MFMA done before overwriting LDS

        // ---- zero As32 (rels only) ----
        if (r < NREL) {
            for (int i = tid; i < BM * APAD / 4; i += 512)
                ((f32x4*)As32)[i] = f32x4{0.f, 0.f, 0.f, 0.f};
        }
        __syncthreads();

        // ---- stage Bs for this rel's K-chunk (swizzled source, linear dest) ----
        int kb = r * CH;
#pragma unroll
        for (int i = 0; i < 4; ++i) {
            int chunk = wid * 4 + i;              // 0..31, 1 KB each
            int crow  = chunk * 4 + (lane >> 4);  // 0..127
            int slot  = (lane & 15) ^ (crow & 15);
            const char* src = (const char*)(Bt + (size_t)crow * KTOT + kb + slot * 8);
            gload_lds16(src, &Bs[chunk * 512]);
        }

        // ---- edge-parallel gather (rels only), one-ahead pipelined ----
        if (r < NREL) {
            int segbase = r * N + n0;
            int beg = offs[segbase];
            int end = offs[r * N + nEnd];
            int e = beg + wid;
            if (e < end) {
                int pk = __builtin_amdgcn_readfirstlane(perm[e]);
                int sn    = pk & 0xFFFFF;
                int local = pk >> 20;
                unsigned v = *(const unsigned*)(xb + (size_t)sn * CH + lane * 2);
                float inv  = invcnt[segbase + local];
                for (; e < end; e += 8) {
                    // prefetch next edge
                    int pk_n = 0;
                    if (e + 8 < end) pk_n = __builtin_amdgcn_readfirstlane(perm[e + 8]);
                    unsigned v_n = 0; float inv_n = 0.f;
                    if (e + 8 < end) {
                        int sn_n = pk_n & 0xFFFFF;
                        v_n   = *(const unsigned*)(xb + (size_t)sn_n * CH + lane * 2);
                        inv_n = invcnt[segbase + (pk_n >> 20)];
                    }
                    // consume current
                    union { unsigned u; float f; } lo, hi;
                    lo.u = v << 16;
                    hi.u = v & 0xFFFF0000u;
                    float* ap = &As32[local * APAD + lane * 2];
                    atomicAdd(ap,     lo.f * inv);
                    atomicAdd(ap + 1, hi.f * inv);
                    v = v_n; inv = inv_n; local = pk_n >> 20;
                }
            }
        }
        __syncthreads();   // atomics + Bs stage complete

        // ---- MFMA: 4 K-steps of 32 ----
#pragma unroll
        for (int ks = 0; ks < 4; ++ks) {
            short8v a[2], b[2];
#pragma unroll
            for (int mr = 0; mr < 2; ++mr) {
                int row = wm * 32 + mr * 16 + r15;
                if (r < NREL) {
                    const float* ap = &As32[row * APAD + ks * 32 + kg * 8];
                    f32x4 v0 = *(const f32x4*)ap;
                    f32x4 v1 = *(const f32x4*)(ap + 4);
                    union { short8v s; unsigned u[4]; } au;
                    au.u[0] = f2bf(v0[0]) | ((unsigned)f2bf(v0[1]) << 16);
                    au.u[1] = f2bf(v0[2]) | ((unsigned)f2bf(v0[3]) << 16);
                    au.u[2] = f2bf(v1[0]) | ((unsigned)f2bf(v1[1]) << 16);
                    au.u[3] = f2bf(v1[2]) | ((unsigned)f2bf(v1[3]) << 16);
                    a[mr] = au.s;
                } else {
                    int gr = n0 + row; if (gr >= N) gr = N - 1;
                    a[mr] = *(const short8v*)(xb + (size_t)gr * CH + ks * 32 + kg * 8);
                }
            }
#pragma unroll
            for (int nc = 0; nc < 2; ++nc) {
                int c = wn * 32 + nc * 16 + r15;
                int p = (ks * 4 + kg) ^ (c & 15);
                b[nc] = *(const short8v*)&Bs[c * CH + p * 8];
            }
#pragma unroll
            for (int mr = 0; mr < 2; ++mr)
#pragma unroll
                for (int nc = 0; nc < 2; ++nc)
                    acc[mr][nc] = __builtin_amdgcn_mfma_f32_16x16x32_bf16(
                        a[mr], b[nc], acc[mr][nc], 0, 0, 0);
        }
    }

    // ---- epilogue: C/D layout col = lane&15, row = (lane>>4)*4 + reg ----
#pragma unroll
    for (int mr = 0; mr < 2; ++mr) {
#pragma unroll
        for (int reg = 0; reg < 4; ++reg) {
            int gr = n0 + wm * 32 + mr * 16 + kg * 4 + reg;
            if (gr >= N) continue;
#pragma unroll
            for (int nc = 0; nc < 2; ++nc) {
                int gc = wn * 32 + nc * 16 + r15;
                float val = acc[mr][nc][reg] + bias[gc];
                out[(size_t)gr * CH + gc] = fmaxf(val, 0.f);
            }
        }
    }
}

extern "C" void kernel_launch(void* const* d_in, const int* in_sizes, int n_in,
                              void* d_out, int out_size, void* d_ws, size_t ws_size,
                              hipStream_t stream)
{
    const float* x    = (const float*)d_in[0];
    const int*   ei   = (const int*)d_in[1];
    const int*   et   = (const int*)d_in[2];
    const float* W    = (const float*)d_in[3];
    const float* root = (const float*)d_in[4];
    const float* bias = (const float*)d_in[5];
    float*       out  = (float*)d_out;

    int N = in_sizes[0] / CH;
    int E = in_sizes[2];
    const int* src = ei;
    const int* dst = ei + E;

    int S  = N * NREL;
    int NB = (S + SCAN_CHUNK - 1) / SCAN_CHUNK;

    // workspace layout
    unsigned short* xb = (unsigned short*)d_ws;               // N*128
    unsigned short* Bt = xb + (size_t)N * CH;                 // 128*1152
    int* hist     = (int*)(Bt + (size_t)CH * KTOT);           // S
    int* cursor   = hist + S;                                 // S
    int* offs     = cursor + S;                               // S+1
    int* partials = offs + S + 1;                             // 256
    float* invcnt = (float*)(partials + 256);                 // S
    int* perm     = (int*)(invcnt + S);                       // E

    hipMemsetAsync(hist, 0, (size_t)2 * S * sizeof(int), stream);

    int total4 = N * CH / 4;
    cvtx_kernel<<<(total4 + 255) / 256, 256, 0, stream>>>(x, xb, total4);
    bt_kernel<<<(CH * KTOT + 255) / 256, 256, 0, stream>>>(W, root, Bt);
    hist_kernel<<<1024, 256, 0, stream>>>(dst, et, hist, E, N);
    scan1_kernel<<<NB, SCAN_THREADS, 0, stream>>>(hist, offs, partials, S);
    scan2_kernel<<<1, SCAN_THREADS, 0, stream>>>(partials, NB);
    finalize_kernel<<<(S + 256) / 256, 256, 0, stream>>>(offs, partials, hist, invcnt, S, E);
    fill_kernel<<<1024, 256, 0, stream>>>(src, dst, et, offs, cursor, perm, E, N);
    fused_kernel<<<(N + BM - 1) / BM, 512, 0, stream>>>(xb, Bt, perm, offs, invcnt, bias, out, N);
}

// Round 6
// 466.668 us; speedup vs baseline: 3.0589x; 3.0589x over previous
//
#include <hip/hip_runtime.h>

#define NREL 8
#define CH   128                 // IN_CH == HID == 128
#define YW   1152                // y row width: 8 rels + root, each 128
#define NCB  9                   // col-blocks of 128 in ygemm

#define SCAN_ITEMS   16
#define SCAN_THREADS 256
#define SCAN_CHUNK   (SCAN_ITEMS * SCAN_THREADS)   // 4096
#define SCAN_SHIFT   12

typedef short  short8v __attribute__((ext_vector_type(8)));
typedef float  f32x4   __attribute__((ext_vector_type(4)));

__device__ __forceinline__ unsigned short f2bf(float f) {
    union { float f; unsigned u; } v; v.f = f;
    return (unsigned short)((v.u + 0x7FFFu + ((v.u >> 16) & 1u)) >> 16);
}
__device__ __forceinline__ void gload_lds16(const void* g, void* l) {
    __builtin_amdgcn_global_load_lds(
        (const __attribute__((address_space(1))) unsigned int*)g,
        (__attribute__((address_space(3))) unsigned int*)l, 16, 0, 0);
}

// ---------------------------------------------------------------------------
// 0. Bt2[rc][k] = bf16( Wcat[k][rc] ); rc = r*128+c, r<8 -> W[r][k][c],
//    r==8 -> root[k][c].  Layout [1152][128], 295 KB (L2-resident).
// ---------------------------------------------------------------------------
__global__ __launch_bounds__(256) void bt2_kernel(
    const float* __restrict__ W, const float* __restrict__ root,
    unsigned short* __restrict__ Bt2)
{
    int idx = blockIdx.x * blockDim.x + threadIdx.x;   // rc*128 + k
    if (idx >= YW * CH) return;
    int rc = idx >> 7, k = idx & 127;
    int r = rc >> 7, c = rc & 127;
    float v = (r < NREL) ? W[(size_t)(r * CH + k) * CH + c]
                         : root[(size_t)k * CH + c];
    Bt2[idx] = f2bf(v);
}

// ---------------------------------------------------------------------------
// 1. histogram over node-major segments seg = dst*8 + et
// ---------------------------------------------------------------------------
__global__ __launch_bounds__(256) void hist_kernel(
    const int* __restrict__ dst, const int* __restrict__ et,
    int* __restrict__ hist, int E)
{
    int stride = gridDim.x * blockDim.x;
    for (int e = blockIdx.x * blockDim.x + threadIdx.x; e < E; e += stride)
        atomicAdd(&hist[dst[e] * NREL + et[e]], 1);
}

// ---------------------------------------------------------------------------
// 2a/2b. two-level exclusive scan
// ---------------------------------------------------------------------------
__global__ __launch_bounds__(SCAN_THREADS) void scan1_kernel(
    const int* __restrict__ hist, int* __restrict__ offs,
    int* __restrict__ partials, int S)
{
    __shared__ int lds[SCAN_THREADS];
    int t = threadIdx.x;
    int base = blockIdx.x * SCAN_CHUNK + t * SCAN_ITEMS;
    int v[SCAN_ITEMS];
    int s = 0;
#pragma unroll
    for (int j = 0; j < SCAN_ITEMS; j++) {
        int idx = base + j;
        int h = (idx < S) ? hist[idx] : 0;
        v[j] = s; s += h;
    }
    int run = s;
    lds[t] = run; __syncthreads();
    for (int off = 1; off < SCAN_THREADS; off <<= 1) {
        int y = (t >= off) ? lds[t - off] : 0;
        __syncthreads();
        run += y; lds[t] = run; __syncthreads();
    }
    int tb = run - s;
    if (t == SCAN_THREADS - 1) partials[blockIdx.x] = run;
#pragma unroll
    for (int j = 0; j < SCAN_ITEMS; j++) {
        int idx = base + j;
        if (idx < S) offs[idx] = tb + v[j];
    }
}

__global__ __launch_bounds__(SCAN_THREADS) void scan2_kernel(
    int* __restrict__ partials, int NB)
{
    __shared__ int lds[SCAN_THREADS];
    int t = threadIdx.x;
    int s = (t < NB) ? partials[t] : 0;
    int run = s;
    lds[t] = run; __syncthreads();
    for (int off = 1; off < SCAN_THREADS; off <<= 1) {
        int y = (t >= off) ? lds[t - off] : 0;
        __syncthreads();
        run += y; lds[t] = run; __syncthreads();
    }
    if (t < NB) partials[t] = run - s;
}

// ---------------------------------------------------------------------------
// 2c. make offs absolute; append sentinel offs[S] = E
// ---------------------------------------------------------------------------
__global__ __launch_bounds__(256) void finalize_kernel(
    int* __restrict__ offs, const int* __restrict__ partials, int S, int E)
{
    int i = blockIdx.x * blockDim.x + threadIdx.x;
    if (i < S)       offs[i] += partials[i >> SCAN_SHIFT];
    else if (i == S) offs[i] = E;
}

// ---------------------------------------------------------------------------
// 3. fill permutation: perm[pos] = src  (node-major segments)
// ---------------------------------------------------------------------------
__global__ __launch_bounds__(256) void fill_kernel(
    const int* __restrict__ src, const int* __restrict__ dst,
    const int* __restrict__ et, const int* __restrict__ offs,
    int* __restrict__ cursor, int* __restrict__ perm, int E)
{
    int stride = gridDim.x * blockDim.x;
    for (int e = blockIdx.x * blockDim.x + threadIdx.x; e < E; e += stride) {
        int seg = dst[e] * NREL + et[e];
        int pos = offs[seg] + atomicAdd(&cursor[seg], 1);
        perm[pos] = src[e];
    }
}

// ---------------------------------------------------------------------------
// 4. ygemm: y[n][rc] = bf16( sum_k x[n][k] * Bt2[rc][k] )
//    Block = 128 rows; A staged once (cvt fp32->bf16, XOR-swizzled slots),
//    loop 9 col-blocks: stage Bs (gload_lds, swizzled source), 4 MFMA
//    K-steps, epilogue bf16 stores. 8 waves: wm=wid>>2 (64 rows), wn=wid&3
//    (32 cols).
// ---------------------------------------------------------------------------
__global__ __launch_bounds__(512) void ygemm_kernel(
    const float* __restrict__ x,
    const unsigned short* __restrict__ Bt2,   // [1152][128]
    unsigned short* __restrict__ y,           // [N][1152]
    int N)
{
    __shared__ __align__(16) unsigned short As[128 * 128];  // 32 KB
    __shared__ __align__(16) unsigned short Bs[128 * 128];  // 32 KB

    int tid  = threadIdx.x;
    int lane = tid & 63;
    int wid  = tid >> 6;
    int wm   = wid >> 2;       // 0..1
    int wn   = wid & 3;        // 0..3
    int r15  = lane & 15;
    int kg   = lane >> 4;      // 0..3
    int n0   = blockIdx.x * 128;

    // ---- stage A once: thread covers (row = tid>>2, k-quarter = tid&3) ----
    {
        int row = tid >> 2;
        int kq  = tid & 3;
        int gn  = n0 + row; if (gn >= N) gn = N - 1;
        const float* xp = x + (size_t)gn * CH + kq * 32;
#pragma unroll
        for (int s8 = 0; s8 < 4; ++s8) {
            float4 f0 = *(const float4*)(xp + s8 * 8);
            float4 f1 = *(const float4*)(xp + s8 * 8 + 4);
            uint4 v;
            v.x = f2bf(f0.x) | ((unsigned)f2bf(f0.y) << 16);
            v.y = f2bf(f0.z) | ((unsigned)f2bf(f0.w) << 16);
            v.z = f2bf(f1.x) | ((unsigned)f2bf(f1.y) << 16);
            v.w = f2bf(f1.z) | ((unsigned)f2bf(f1.w) << 16);
            int slot = kq * 4 + s8;
            int phys = slot ^ (row & 15);
            *(uint4*)&As[row * 128 + phys * 8] = v;
        }
    }

    for (int cb = 0; cb < NCB; ++cb) {
        // ---- stage Bs for this col-block (linear dest, swizzled source) ----
#pragma unroll
        for (int i = 0; i < 4; ++i) {
            int chunk = wid * 4 + i;              // 0..31, 1 KB each = 4 cols
            int col   = chunk * 4 + (lane >> 4);
            int slog  = (lane & 15) ^ (col & 15);
            const char* src = (const char*)(Bt2 + (size_t)(cb * CH + col) * CH + slog * 8);
            gload_lds16(src, &Bs[chunk * 512]);
        }
        __syncthreads();   // drains vmcnt (Bs) + lgkm (As on first iter)

        f32x4 acc[4][2];
#pragma unroll
        for (int i = 0; i < 4; i++)
#pragma unroll
            for (int j = 0; j < 2; j++)
                acc[i][j] = f32x4{0.f, 0.f, 0.f, 0.f};

#pragma unroll
        for (int ks = 0; ks < 4; ++ks) {
            short8v a[4], b[2];
#pragma unroll
            for (int mr = 0; mr < 4; ++mr) {
                int row  = wm * 64 + mr * 16 + r15;
                int phys = (ks * 4 + kg) ^ (row & 15);
                a[mr] = *(const short8v*)&As[row * 128 + phys * 8];
            }
#pragma unroll
            for (int nc = 0; nc < 2; ++nc) {
                int col  = wn * 32 + nc * 16 + r15;
                int phys = (ks * 4 + kg) ^ (col & 15);
                b[nc] = *(const short8v*)&Bs[col * 128 + phys * 8];
            }
#pragma unroll
            for (int mr = 0; mr < 4; ++mr)
#pragma unroll
                for (int nc = 0; nc < 2; ++nc)
                    acc[mr][nc] = __builtin_amdgcn_mfma_f32_16x16x32_bf16(
                        a[mr], b[nc], acc[mr][nc], 0, 0, 0);
        }

        // ---- epilogue: C/D layout col = lane&15, row = (lane>>4)*4+reg ----
#pragma unroll
        for (int mr = 0; mr < 4; ++mr) {
#pragma unroll
            for (int reg = 0; reg < 4; ++reg) {
                int gr = n0 + wm * 64 + mr * 16 + kg * 4 + reg;
                if (gr >= N) continue;
#pragma unroll
                for (int nc = 0; nc < 2; ++nc) {
                    int gc = cb * CH + wn * 32 + nc * 16 + r15;
                    y[(size_t)gr * YW + gc] = f2bf(acc[mr][nc][reg]);
                }
            }
        }
        __syncthreads();   // all LDS reads done before next Bs overwrite
    }
}

// ---------------------------------------------------------------------------
// 5. gather: out[n] = relu( sum_r mean_{e in seg(n,r)} y_r[perm[e]]
//                           + y_root[n] + bias )
//    2 waves per node (4 rels each), LDS combine. 64 lanes x 2 ch.
// ---------------------------------------------------------------------------
__global__ __launch_bounds__(512) void gather_kernel(
    const unsigned short* __restrict__ y,
    const int* __restrict__ perm,
    const int* __restrict__ offs,
    const float* __restrict__ bias,
    float* __restrict__ out, int N)
{
    __shared__ float part[4][CH];
    int tid  = threadIdx.x;
    int lane = tid & 63;
    int wid  = tid >> 6;
    int nl   = wid >> 1;          // node-local 0..3
    int half = wid & 1;
    int n    = blockIdx.x * 4 + nl;
    bool valid = n < N;
    int nc   = valid ? n : N - 1;

    const int* op = offs + (size_t)nc * NREL + half * 4;
    int b0 = op[0], b1 = op[1], b2 = op[2], b3 = op[3], b4 = op[4];

    float s0 = 0.f, s1 = 0.f;
    const unsigned short* ybase = y + (size_t)half * 4 * CH + lane * 2;

#define DO_REL(RI, BEG, END)                                                  \
    {                                                                         \
        float a0 = 0.f, a1 = 0.f;                                             \
        for (int e = (BEG); e < (END); ++e) {                                 \
            int s = perm[e];                                                  \
            unsigned u = *(const unsigned*)(ybase + (size_t)s * YW + (RI) * CH); \
            union { unsigned uu; float ff; } lo, hi;                          \
            lo.uu = u << 16; hi.uu = u & 0xFFFF0000u;                         \
            a0 += lo.ff; a1 += hi.ff;                                         \
        }                                                                     \
        if ((END) > (BEG)) {                                                  \
            float inv = 1.0f / (float)((END) - (BEG));                        \
            s0 += a0 * inv; s1 += a1 * inv;                                   \
        }                                                                     \
    }

    DO_REL(0, b0, b1)
    DO_REL(1, b1, b2)
    DO_REL(2, b2, b3)
    DO_REL(3, b3, b4)
#undef DO_REL

    if (half == 1) {
        part[nl][lane * 2]     = s0;
        part[nl][lane * 2 + 1] = s1;
    }
    __syncthreads();
    if (half == 0 && valid) {
        unsigned ur = *(const unsigned*)(y + (size_t)nc * YW + NREL * CH + lane * 2);
        union { unsigned uu; float ff; } lo, hi;
        lo.uu = ur << 16; hi.uu = ur & 0xFFFF0000u;
        float o0 = s0 + lo.ff + part[nl][lane * 2]     + bias[lane * 2];
        float o1 = s1 + hi.ff + part[nl][lane * 2 + 1] + bias[lane * 2 + 1];
        float2 ov;
        ov.x = fmaxf(o0, 0.f);
        ov.y = fmaxf(o1, 0.f);
        *(float2*)(out + (size_t)n * CH + lane * 2) = ov;
    }
}

extern "C" void kernel_launch(void* const* d_in, const int* in_sizes, int n_in,
                              void* d_out, int out_size, void* d_ws, size_t ws_size,
                              hipStream_t stream)
{
    const float* x    = (const float*)d_in[0];
    const int*   ei   = (const int*)d_in[1];
    const int*   et   = (const int*)d_in[2];
    const float* W    = (const float*)d_in[3];
    const float* root = (const float*)d_in[4];
    const float* bias = (const float*)d_in[5];
    float*       out  = (float*)d_out;

    int N = in_sizes[0] / CH;
    int E = in_sizes[2];
    const int* src = ei;
    const int* dst = ei + E;

    int S  = N * NREL;
    int NB = (S + SCAN_CHUNK - 1) / SCAN_CHUNK;

    // workspace layout (~247 MB)
    unsigned short* y   = (unsigned short*)d_ws;              // N*1152 bf16
    unsigned short* Bt2 = y + (size_t)N * YW;                 // 1152*128 bf16
    int* hist     = (int*)(Bt2 + (size_t)YW * CH);            // S
    int* cursor   = hist + S;                                 // S
    int* offs     = cursor + S;                               // S+1
    int* partials = offs + S + 1;                             // 256
    int* perm     = partials + 256;                           // E

    hipMemsetAsync(hist, 0, (size_t)2 * S * sizeof(int), stream);

    bt2_kernel<<<(YW * CH + 255) / 256, 256, 0, stream>>>(W, root, Bt2);
    hist_kernel<<<1024, 256, 0, stream>>>(dst, et, hist, E);
    scan1_kernel<<<NB, SCAN_THREADS, 0, stream>>>(hist, offs, partials, S);
    scan2_kernel<<<1, SCAN_THREADS, 0, stream>>>(partials, NB);
    finalize_kernel<<<(S + 256) / 256, 256, 0, stream>>>(offs, partials, S, E);
    fill_kernel<<<1024, 256, 0, stream>>>(src, dst, et, offs, cursor, perm, E);
    ygemm_kernel<<<(N + 127) / 128, 512, 0, stream>>>(x, Bt2, y, N);
    gather_kernel<<<(N + 3) / 4, 512, 0, stream>>>(y, perm, offs, bias, out, N);
}

// Round 7
// 379.308 us; speedup vs baseline: 3.7635x; 1.2303x over previous
//
#include <hip/hip_runtime.h>

#define NREL 8
#define CH   128                 // IN_CH == HID == 128
#define YW   1152                // y row width: 8 rels + root, each 128
#define YWD  (YW / 2)            // y row width in dwords (576)
#define NCB  9                   // col-blocks of 128 in ygemm

#define SCAN_ITEMS   16
#define SCAN_THREADS 256
#define SCAN_CHUNK   (SCAN_ITEMS * SCAN_THREADS)   // 4096
#define SCAN_SHIFT   12

typedef short  short8v __attribute__((ext_vector_type(8)));
typedef float  f32x4   __attribute__((ext_vector_type(4)));

__device__ __forceinline__ unsigned short f2bf(float f) {
    union { float f; unsigned u; } v; v.f = f;
    return (unsigned short)((v.u + 0x7FFFu + ((v.u >> 16) & 1u)) >> 16);
}
__device__ __forceinline__ float lof(unsigned u) {
    union { unsigned u; float f; } v; v.u = u << 16; return v.f;
}
__device__ __forceinline__ float hif(unsigned u) {
    union { unsigned u; float f; } v; v.u = u & 0xFFFF0000u; return v.f;
}
__device__ __forceinline__ void gload_lds16(const void* g, void* l) {
    __builtin_amdgcn_global_load_lds(
        (const __attribute__((address_space(1))) unsigned int*)g,
        (__attribute__((address_space(3))) unsigned int*)l, 16, 0, 0);
}

// ---------------------------------------------------------------------------
// 0. Bt2[rc][k] = bf16( Wcat[k][rc] ); rc = r*128+c
// ---------------------------------------------------------------------------
__global__ __launch_bounds__(256) void bt2_kernel(
    const float* __restrict__ W, const float* __restrict__ root,
    unsigned short* __restrict__ Bt2)
{
    int idx = blockIdx.x * blockDim.x + threadIdx.x;   // rc*128 + k
    if (idx >= YW * CH) return;
    int rc = idx >> 7, k = idx & 127;
    int r = rc >> 7, c = rc & 127;
    float v = (r < NREL) ? W[(size_t)(r * CH + k) * CH + c]
                         : root[(size_t)k * CH + c];
    Bt2[idx] = f2bf(v);
}

// ---------------------------------------------------------------------------
// 1. histogram over node-major segments seg = dst*8 + et
// ---------------------------------------------------------------------------
__global__ __launch_bounds__(256) void hist_kernel(
    const int* __restrict__ dst, const int* __restrict__ et,
    int* __restrict__ hist, int E)
{
    int stride = gridDim.x * blockDim.x;
    for (int e = blockIdx.x * blockDim.x + threadIdx.x; e < E; e += stride)
        atomicAdd(&hist[dst[e] * NREL + et[e]], 1);
}

// ---------------------------------------------------------------------------
// 2a/2b. two-level exclusive scan
// ---------------------------------------------------------------------------
__global__ __launch_bounds__(SCAN_THREADS) void scan1_kernel(
    const int* __restrict__ hist, int* __restrict__ offs,
    int* __restrict__ partials, int S)
{
    __shared__ int lds[SCAN_THREADS];
    int t = threadIdx.x;
    int base = blockIdx.x * SCAN_CHUNK + t * SCAN_ITEMS;
    int v[SCAN_ITEMS];
    int s = 0;
#pragma unroll
    for (int j = 0; j < SCAN_ITEMS; j++) {
        int idx = base + j;
        int h = (idx < S) ? hist[idx] : 0;
        v[j] = s; s += h;
    }
    int run = s;
    lds[t] = run; __syncthreads();
    for (int off = 1; off < SCAN_THREADS; off <<= 1) {
        int y = (t >= off) ? lds[t - off] : 0;
        __syncthreads();
        run += y; lds[t] = run; __syncthreads();
    }
    int tb = run - s;
    if (t == SCAN_THREADS - 1) partials[blockIdx.x] = run;
#pragma unroll
    for (int j = 0; j < SCAN_ITEMS; j++) {
        int idx = base + j;
        if (idx < S) offs[idx] = tb + v[j];
    }
}

__global__ __launch_bounds__(SCAN_THREADS) void scan2_kernel(
    int* __restrict__ partials, int NB)
{
    __shared__ int lds[SCAN_THREADS];
    int t = threadIdx.x;
    int s = (t < NB) ? partials[t] : 0;
    int run = s;
    lds[t] = run; __syncthreads();
    for (int off = 1; off < SCAN_THREADS; off <<= 1) {
        int y = (t >= off) ? lds[t - off] : 0;
        __syncthreads();
        run += y; lds[t] = run; __syncthreads();
    }
    if (t < NB) partials[t] = run - s;
}

// ---------------------------------------------------------------------------
// 2c. offs -> absolute (+sentinel); invcnt[i] = 1/max(hist[i],1)
// ---------------------------------------------------------------------------
__global__ __launch_bounds__(256) void finalize_kernel(
    int* __restrict__ offs, const int* __restrict__ partials,
    const int* __restrict__ hist, float* __restrict__ invcnt, int S, int E)
{
    int i = blockIdx.x * blockDim.x + threadIdx.x;
    if (i < S) {
        offs[i] += partials[i >> SCAN_SHIFT];
        invcnt[i] = 1.0f / (float)max(hist[i], 1);
    } else if (i == S) offs[i] = E;
}

// ---------------------------------------------------------------------------
// 3. fill: perm[pos] = src*9 + rel (direct y-row index), wgt[pos] = invcnt
// ---------------------------------------------------------------------------
__global__ __launch_bounds__(256) void fill_kernel(
    const int* __restrict__ src, const int* __restrict__ dst,
    const int* __restrict__ et, const int* __restrict__ offs,
    const float* __restrict__ invcnt, int* __restrict__ cursor,
    int* __restrict__ perm, float* __restrict__ wgt, int E)
{
    int stride = gridDim.x * blockDim.x;
    for (int e = blockIdx.x * blockDim.x + threadIdx.x; e < E; e += stride) {
        int r = et[e];
        int seg = dst[e] * NREL + r;
        int pos = offs[seg] + atomicAdd(&cursor[seg], 1);
        perm[pos] = src[e] * 9 + r;
        wgt[pos]  = invcnt[seg];
    }
}

// ---------------------------------------------------------------------------
// 4. ygemm: y[n][rc] = bf16( sum_k x[n][k] * Bt2[rc][k] )   (unchanged R6)
// ---------------------------------------------------------------------------
__global__ __launch_bounds__(512) void ygemm_kernel(
    const float* __restrict__ x,
    const unsigned short* __restrict__ Bt2,   // [1152][128]
    unsigned short* __restrict__ y,           // [N][1152]
    int N)
{
    __shared__ __align__(16) unsigned short As[128 * 128];  // 32 KB
    __shared__ __align__(16) unsigned short Bs[128 * 128];  // 32 KB

    int tid  = threadIdx.x;
    int lane = tid & 63;
    int wid  = tid >> 6;
    int wm   = wid >> 2;       // 0..1
    int wn   = wid & 3;        // 0..3
    int r15  = lane & 15;
    int kg   = lane >> 4;      // 0..3
    int n0   = blockIdx.x * 128;

    // ---- stage A once ----
    {
        int row = tid >> 2;
        int kq  = tid & 3;
        int gn  = n0 + row; if (gn >= N) gn = N - 1;
        const float* xp = x + (size_t)gn * CH + kq * 32;
#pragma unroll
        for (int s8 = 0; s8 < 4; ++s8) {
            float4 f0 = *(const float4*)(xp + s8 * 8);
            float4 f1 = *(const float4*)(xp + s8 * 8 + 4);
            uint4 v;
            v.x = f2bf(f0.x) | ((unsigned)f2bf(f0.y) << 16);
            v.y = f2bf(f0.z) | ((unsigned)f2bf(f0.w) << 16);
            v.z = f2bf(f1.x) | ((unsigned)f2bf(f1.y) << 16);
            v.w = f2bf(f1.z) | ((unsigned)f2bf(f1.w) << 16);
            int slot = kq * 4 + s8;
            int phys = slot ^ (row & 15);
            *(uint4*)&As[row * 128 + phys * 8] = v;
        }
    }

    for (int cb = 0; cb < NCB; ++cb) {
#pragma unroll
        for (int i = 0; i < 4; ++i) {
            int chunk = wid * 4 + i;
            int col   = chunk * 4 + (lane >> 4);
            int slog  = (lane & 15) ^ (col & 15);
            const char* srcp = (const char*)(Bt2 + (size_t)(cb * CH + col) * CH + slog * 8);
            gload_lds16(srcp, &Bs[chunk * 512]);
        }
        __syncthreads();

        f32x4 acc[4][2];
#pragma unroll
        for (int i = 0; i < 4; i++)
#pragma unroll
            for (int j = 0; j < 2; j++)
                acc[i][j] = f32x4{0.f, 0.f, 0.f, 0.f};

#pragma unroll
        for (int ks = 0; ks < 4; ++ks) {
            short8v a[4], b[2];
#pragma unroll
            for (int mr = 0; mr < 4; ++mr) {
                int row  = wm * 64 + mr * 16 + r15;
                int phys = (ks * 4 + kg) ^ (row & 15);
                a[mr] = *(const short8v*)&As[row * 128 + phys * 8];
            }
#pragma unroll
            for (int nc = 0; nc < 2; ++nc) {
                int col  = wn * 32 + nc * 16 + r15;
                int phys = (ks * 4 + kg) ^ (col & 15);
                b[nc] = *(const short8v*)&Bs[col * 128 + phys * 8];
            }
#pragma unroll
            for (int mr = 0; mr < 4; ++mr)
#pragma unroll
                for (int nc = 0; nc < 2; ++nc)
                    acc[mr][nc] = __builtin_amdgcn_mfma_f32_16x16x32_bf16(
                        a[mr], b[nc], acc[mr][nc], 0, 0, 0);
        }

#pragma unroll
        for (int mr = 0; mr < 4; ++mr) {
#pragma unroll
            for (int reg = 0; reg < 4; ++reg) {
                int gr = n0 + wm * 64 + mr * 16 + kg * 4 + reg;
                if (gr >= N) continue;
#pragma unroll
                for (int nc = 0; nc < 2; ++nc) {
                    int gc = cb * CH + wn * 32 + nc * 16 + r15;
                    y[(size_t)gr * YW + gc] = f2bf(acc[mr][nc][reg]);
                }
            }
        }
        __syncthreads();
    }
}

// ---------------------------------------------------------------------------
// 5. gather: out[n] = relu( sum_{e in node n} wgt[e]*y[perm[e]*128 ..]
//                           + y_root[n] + bias )
//    One wave per node, contiguous edge range, shfl-broadcast edge meta,
//    unroll-8 row loads for MLP.
// ---------------------------------------------------------------------------
__global__ __launch_bounds__(256) void gather_kernel(
    const unsigned short* __restrict__ y,
    const int* __restrict__ perm,
    const float* __restrict__ wgt,
    const int* __restrict__ offs,
    const float* __restrict__ bias,
    float* __restrict__ out, int N)
{
    int wid  = threadIdx.x >> 6;
    int lane = threadIdx.x & 63;
    int n    = blockIdx.x * 4 + wid;
    if (n >= N) return;

    int beg = offs[n * NREL];
    int end = offs[n * NREL + NREL];
    const unsigned* y32 = (const unsigned*)y;

    float a0 = 0.f, a1 = 0.f;

    for (int blk = beg; blk < end; blk += 64) {
        int m = end - blk; if (m > 64) m = 64;
        int   pv = 0;
        float wv = 0.f;
        if (lane < m) { pv = perm[blk + lane]; wv = wgt[blk + lane]; }

        int j = 0;
#define EDGE_LOAD(K) \
            int   p##K = __shfl(pv, j + K);                     \
            float w##K = __shfl(wv, j + K);                     \
            unsigned u##K = y32[(size_t)p##K * 64 + lane];
#define EDGE_ACC(K) \
            a0 += w##K * lof(u##K); a1 += w##K * hif(u##K);

        for (; j + 8 <= m; j += 8) {
            EDGE_LOAD(0) EDGE_LOAD(1) EDGE_LOAD(2) EDGE_LOAD(3)
            EDGE_LOAD(4) EDGE_LOAD(5) EDGE_LOAD(6) EDGE_LOAD(7)
            EDGE_ACC(0) EDGE_ACC(1) EDGE_ACC(2) EDGE_ACC(3)
            EDGE_ACC(4) EDGE_ACC(5) EDGE_ACC(6) EDGE_ACC(7)
        }
        if (j + 4 <= m) {
            EDGE_LOAD(0) EDGE_LOAD(1) EDGE_LOAD(2) EDGE_LOAD(3)
            EDGE_ACC(0) EDGE_ACC(1) EDGE_ACC(2) EDGE_ACC(3)
            j += 4;
        }
        for (; j < m; ++j) {
            EDGE_LOAD(0)
            EDGE_ACC(0)
        }
#undef EDGE_LOAD
#undef EDGE_ACC
    }

    // root + bias + relu
    unsigned ur = y32[(size_t)n * YWD + (NREL * CH / 2) + lane];
    float o0 = a0 + lof(ur) + bias[lane * 2];
    float o1 = a1 + hif(ur) + bias[lane * 2 + 1];
    float2 ov;
    ov.x = fmaxf(o0, 0.f);
    ov.y = fmaxf(o1, 0.f);
    *(float2*)(out + (size_t)n * CH + lane * 2) = ov;
}

extern "C" void kernel_launch(void* const* d_in, const int* in_sizes, int n_in,
                              void* d_out, int out_size, void* d_ws, size_t ws_size,
                              hipStream_t stream)
{
    const float* x    = (const float*)d_in[0];
    const int*   ei   = (const int*)d_in[1];
    const int*   et   = (const int*)d_in[2];
    const float* W    = (const float*)d_in[3];
    const float* root = (const float*)d_in[4];
    const float* bias = (const float*)d_in[5];
    float*       out  = (float*)d_out;

    int N = in_sizes[0] / CH;
    int E = in_sizes[2];
    const int* src = ei;
    const int* dst = ei + E;

    int S  = N * NREL;
    int NB = (S + SCAN_CHUNK - 1) / SCAN_CHUNK;

    // workspace layout (~250 MB)
    unsigned short* y   = (unsigned short*)d_ws;              // N*1152 bf16
    unsigned short* Bt2 = y + (size_t)N * YW;                 // 1152*128 bf16
    int* hist     = (int*)(Bt2 + (size_t)YW * CH);            // S
    int* cursor   = hist + S;                                 // S
    int* offs     = cursor + S;                               // S+1
    int* partials = offs + S + 1;                             // 256
    float* invcnt = (float*)(partials + 256);                 // S
    int* perm     = (int*)(invcnt + S);                       // E
    float* wgt    = (float*)(perm + E);                       // E

    hipMemsetAsync(hist, 0, (size_t)2 * S * sizeof(int), stream);

    bt2_kernel<<<(YW * CH + 255) / 256, 256, 0, stream>>>(W, root, Bt2);
    hist_kernel<<<1024, 256, 0, stream>>>(dst, et, hist, E);
    scan1_kernel<<<NB, SCAN_THREADS, 0, stream>>>(hist, offs, partials, S);
    scan2_kernel<<<1, SCAN_THREADS, 0, stream>>>(partials, NB);
    finalize_kernel<<<(S + 256) / 256, 256, 0, stream>>>(offs, partials, hist, invcnt, S, E);
    fill_kernel<<<1024, 256, 0, stream>>>(src, dst, et, offs, invcnt, cursor, perm, wgt, E);
    ygemm_kernel<<<(N + 127) / 128, 512, 0, stream>>>(x, Bt2, y, N);
    gather_kernel<<<(N + 3) / 4, 256, 0, stream>>>(y, perm, wgt, offs, bias, out, N);
}

// Round 8
// 336.539 us; speedup vs baseline: 4.2417x; 1.1271x over previous
//
#include <hip/hip_runtime.h>

#define NREL 8
#define CH   128                 // IN_CH == HID == 128
#define YW   1152                // y row width: 8 rels + root, each 128
#define YWD  (YW / 2)            // y row width in dwords (576)
#define NCB  9                   // col-blocks of 128 in ygemm

#define SCAN_ITEMS   16
#define SCAN_THREADS 256
#define SCAN_CHUNK   (SCAN_ITEMS * SCAN_THREADS)   // 4096
#define SCAN_SHIFT   12

typedef short  short8v __attribute__((ext_vector_type(8)));
typedef float  f32x4   __attribute__((ext_vector_type(4)));

__device__ __forceinline__ unsigned short f2bf(float f) {
    union { float f; unsigned u; } v; v.f = f;
    return (unsigned short)((v.u + 0x7FFFu + ((v.u >> 16) & 1u)) >> 16);
}
__device__ __forceinline__ float lof(unsigned u) {
    union { unsigned u; float f; } v; v.u = u << 16; return v.f;
}
__device__ __forceinline__ float hif(unsigned u) {
    union { unsigned u; float f; } v; v.u = u & 0xFFFF0000u; return v.f;
}
__device__ __forceinline__ void gload_lds16(const void* g, void* l) {
    __builtin_amdgcn_global_load_lds(
        (const __attribute__((address_space(1))) unsigned int*)g,
        (__attribute__((address_space(3))) unsigned int*)l, 16, 0, 0);
}

// ---------------------------------------------------------------------------
// 0. Bt2[rc][k] = bf16( Wcat[k][rc] ); rc = r*128+c
// ---------------------------------------------------------------------------
__global__ __launch_bounds__(256) void bt2_kernel(
    const float* __restrict__ W, const float* __restrict__ root,
    unsigned short* __restrict__ Bt2)
{
    int idx = blockIdx.x * blockDim.x + threadIdx.x;   // rc*128 + k
    if (idx >= YW * CH) return;
    int rc = idx >> 7, k = idx & 127;
    int r = rc >> 7, c = rc & 127;
    float v = (r < NREL) ? W[(size_t)(r * CH + k) * CH + c]
                         : root[(size_t)k * CH + c];
    Bt2[idx] = f2bf(v);
}

// ---------------------------------------------------------------------------
// 1. histogram over node-major segments seg = dst*8 + et
// ---------------------------------------------------------------------------
__global__ __launch_bounds__(256) void hist_kernel(
    const int* __restrict__ dst, const int* __restrict__ et,
    int* __restrict__ hist, int E)
{
    int e = blockIdx.x * blockDim.x + threadIdx.x;
    if (e < E) atomicAdd(&hist[dst[e] * NREL + et[e]], 1);
}

// ---------------------------------------------------------------------------
// 2a/2b. two-level exclusive scan (scan1 writes ofs = pad_offs+1)
// ---------------------------------------------------------------------------
__global__ __launch_bounds__(SCAN_THREADS) void scan1_kernel(
    const int* __restrict__ hist, int* __restrict__ ofs,
    int* __restrict__ partials, int S)
{
    __shared__ int lds[SCAN_THREADS];
    int t = threadIdx.x;
    int base = blockIdx.x * SCAN_CHUNK + t * SCAN_ITEMS;
    int v[SCAN_ITEMS];
    int s = 0;
#pragma unroll
    for (int j = 0; j < SCAN_ITEMS; j++) {
        int idx = base + j;
        int h = (idx < S) ? hist[idx] : 0;
        v[j] = s; s += h;
    }
    int run = s;
    lds[t] = run; __syncthreads();
    for (int off = 1; off < SCAN_THREADS; off <<= 1) {
        int y = (t >= off) ? lds[t - off] : 0;
        __syncthreads();
        run += y; lds[t] = run; __syncthreads();
    }
    int tb = run - s;
    if (t == SCAN_THREADS - 1) partials[blockIdx.x] = run;
#pragma unroll
    for (int j = 0; j < SCAN_ITEMS; j++) {
        int idx = base + j;
        if (idx < S) ofs[idx] = tb + v[j];
    }
}

__global__ __launch_bounds__(SCAN_THREADS) void scan2_kernel(
    int* __restrict__ partials, int NB)
{
    __shared__ int lds[SCAN_THREADS];
    int t = threadIdx.x;
    int s = (t < NB) ? partials[t] : 0;
    int run = s;
    lds[t] = run; __syncthreads();
    for (int off = 1; off < SCAN_THREADS; off <<= 1) {
        int y = (t >= off) ? lds[t - off] : 0;
        __syncthreads();
        run += y; lds[t] = run; __syncthreads();
    }
    if (t < NB) partials[t] = run - s;
}

// ---------------------------------------------------------------------------
// 2c. ofs -> absolute; pad_offs[0] = 0
// ---------------------------------------------------------------------------
__global__ __launch_bounds__(256) void finalize_kernel(
    int* __restrict__ ofs, const int* __restrict__ partials,
    int* __restrict__ pad_offs, int S)
{
    int i = blockIdx.x * blockDim.x + threadIdx.x;
    if (i < S) ofs[i] += partials[i >> SCAN_SHIFT];
    if (i == 0) pad_offs[0] = 0;
}

// ---------------------------------------------------------------------------
// 3. fill: pos = atomicAdd(&ofs[seg],1) (DESTRUCTIVE: ofs[i] becomes end of
//    seg i = begin of seg i+1); perm[pos] = src only.
// ---------------------------------------------------------------------------
__global__ __launch_bounds__(256) void fill_kernel(
    const int* __restrict__ src, const int* __restrict__ dst,
    const int* __restrict__ et, int* __restrict__ ofs,
    int* __restrict__ perm, int E)
{
    int e = blockIdx.x * blockDim.x + threadIdx.x;
    if (e >= E) return;
    int seg = dst[e] * NREL + et[e];
    int pos = atomicAdd(&ofs[seg], 1);
    perm[pos] = src[e];
}

// ---------------------------------------------------------------------------
// 4. ygemm: y[n][rc] = bf16( sum_k x[n][k] * Bt2[rc][k] )
// ---------------------------------------------------------------------------
__global__ __launch_bounds__(512) void ygemm_kernel(
    const float* __restrict__ x,
    const unsigned short* __restrict__ Bt2,   // [1152][128]
    unsigned short* __restrict__ y,           // [N][1152]
    int N)
{
    __shared__ __align__(16) unsigned short As[128 * 128];  // 32 KB
    __shared__ __align__(16) unsigned short Bs[128 * 128];  // 32 KB

    int tid  = threadIdx.x;
    int lane = tid & 63;
    int wid  = tid >> 6;
    int wm   = wid >> 2;       // 0..1
    int wn   = wid & 3;        // 0..3
    int r15  = lane & 15;
    int kg   = lane >> 4;      // 0..3
    int n0   = blockIdx.x * 128;

    // ---- stage A once ----
    {
        int row = tid >> 2;
        int kq  = tid & 3;
        int gn  = n0 + row; if (gn >= N) gn = N - 1;
        const float* xp = x + (size_t)gn * CH + kq * 32;
#pragma unroll
        for (int s8 = 0; s8 < 4; ++s8) {
            float4 f0 = *(const float4*)(xp + s8 * 8);
            float4 f1 = *(const float4*)(xp + s8 * 8 + 4);
            uint4 v;
            v.x = f2bf(f0.x) | ((unsigned)f2bf(f0.y) << 16);
            v.y = f2bf(f0.z) | ((unsigned)f2bf(f0.w) << 16);
            v.z = f2bf(f1.x) | ((unsigned)f2bf(f1.y) << 16);
            v.w = f2bf(f1.z) | ((unsigned)f2bf(f1.w) << 16);
            int slot = kq * 4 + s8;
            int phys = slot ^ (row & 15);
            *(uint4*)&As[row * 128 + phys * 8] = v;
        }
    }

    for (int cb = 0; cb < NCB; ++cb) {
#pragma unroll
        for (int i = 0; i < 4; ++i) {
            int chunk = wid * 4 + i;
            int col   = chunk * 4 + (lane >> 4);
            int slog  = (lane & 15) ^ (col & 15);
            const char* srcp = (const char*)(Bt2 + (size_t)(cb * CH + col) * CH + slog * 8);
            gload_lds16(srcp, &Bs[chunk * 512]);
        }
        __syncthreads();

        f32x4 acc[4][2];
#pragma unroll
        for (int i = 0; i < 4; i++)
#pragma unroll
            for (int j = 0; j < 2; j++)
                acc[i][j] = f32x4{0.f, 0.f, 0.f, 0.f};

#pragma unroll
        for (int ks = 0; ks < 4; ++ks) {
            short8v a[4], b[2];
#pragma unroll
            for (int mr = 0; mr < 4; ++mr) {
                int row  = wm * 64 + mr * 16 + r15;
                int phys = (ks * 4 + kg) ^ (row & 15);
                a[mr] = *(const short8v*)&As[row * 128 + phys * 8];
            }
#pragma unroll
            for (int nc = 0; nc < 2; ++nc) {
                int col  = wn * 32 + nc * 16 + r15;
                int phys = (ks * 4 + kg) ^ (col & 15);
                b[nc] = *(const short8v*)&Bs[col * 128 + phys * 8];
            }
#pragma unroll
            for (int mr = 0; mr < 4; ++mr)
#pragma unroll
                for (int nc = 0; nc < 2; ++nc)
                    acc[mr][nc] = __builtin_amdgcn_mfma_f32_16x16x32_bf16(
                        a[mr], b[nc], acc[mr][nc], 0, 0, 0);
        }

#pragma unroll
        for (int mr = 0; mr < 4; ++mr) {
#pragma unroll
            for (int reg = 0; reg < 4; ++reg) {
                int gr = n0 + wm * 64 + mr * 16 + kg * 4 + reg;
                if (gr >= N) continue;
#pragma unroll
                for (int nc = 0; nc < 2; ++nc) {
                    int gc = cb * CH + wn * 32 + nc * 16 + r15;
                    y[(size_t)gr * YW + gc] = f2bf(acc[mr][nc][reg]);
                }
            }
        }
        __syncthreads();
    }
}

// ---------------------------------------------------------------------------
// 5. gather: out[n] = relu( sum_e w_e * y[src_e*9+rel_e] + y_root[n] + bias )
//    One wave per node. Boundaries b0..b8 = pad_offs[n*8 .. n*8+8] (post-fill
//    ends array). Per-lane edge meta: rel/weight from compare chain; shfl
//    broadcast; unroll-8 row loads.
// ---------------------------------------------------------------------------
__global__ __launch_bounds__(256) void gather_kernel(
    const unsigned short* __restrict__ y,
    const int* __restrict__ perm,
    const int* __restrict__ pad_offs,
    const float* __restrict__ bias,
    float* __restrict__ out, int N)
{
    int wid  = threadIdx.x >> 6;
    int lane = threadIdx.x & 63;
    int n    = blockIdx.x * 4 + wid;
    if (n >= N) return;

    const int* bp = pad_offs + n * NREL;
    int b0 = bp[0], b1 = bp[1], b2 = bp[2], b3 = bp[3], b4 = bp[4];
    int b5 = bp[5], b6 = bp[6], b7 = bp[7], b8 = bp[8];

    const unsigned* y32 = (const unsigned*)y;
    float a0 = 0.f, a1 = 0.f;

    for (int blk = b0; blk < b8; blk += 64) {
        int m = b8 - blk; if (m > 64) m = 64;
        int   pv = 0;
        float wv = 0.f;
        if (lane < m) {
            int g   = blk + lane;
            int s   = perm[g];
            int c1 = g >= b1, c2 = g >= b2, c3 = g >= b3, c4 = g >= b4;
            int c5 = g >= b5, c6 = g >= b6, c7 = g >= b7;
            int r  = c1 + c2 + c3 + c4 + c5 + c6 + c7;
            int br  = b0;
            br  = c1 ? b1 : br;  br  = c2 ? b2 : br;  br  = c3 ? b3 : br;
            br  = c4 ? b4 : br;  br  = c5 ? b5 : br;  br  = c6 ? b6 : br;
            br  = c7 ? b7 : br;
            int br1 = b1;
            br1 = c1 ? b2 : br1; br1 = c2 ? b3 : br1; br1 = c3 ? b4 : br1;
            br1 = c4 ? b5 : br1; br1 = c5 ? b6 : br1; br1 = c6 ? b7 : br1;
            br1 = c7 ? b8 : br1;
            pv = s * 9 + r;
            wv = 1.0f / (float)(br1 - br);
        }

        int j = 0;
#define EDGE_LOAD(K) \
            int   p##K = __shfl(pv, j + K);                     \
            float w##K = __shfl(wv, j + K);                     \
            unsigned u##K = y32[(size_t)p##K * 64 + lane];
#define EDGE_ACC(K) \
            a0 += w##K * lof(u##K); a1 += w##K * hif(u##K);

        for (; j + 8 <= m; j += 8) {
            EDGE_LOAD(0) EDGE_LOAD(1) EDGE_LOAD(2) EDGE_LOAD(3)
            EDGE_LOAD(4) EDGE_LOAD(5) EDGE_LOAD(6) EDGE_LOAD(7)
            EDGE_ACC(0) EDGE_ACC(1) EDGE_ACC(2) EDGE_ACC(3)
            EDGE_ACC(4) EDGE_ACC(5) EDGE_ACC(6) EDGE_ACC(7)
        }
        if (j + 4 <= m) {
            EDGE_LOAD(0) EDGE_LOAD(1) EDGE_LOAD(2) EDGE_LOAD(3)
            EDGE_ACC(0) EDGE_ACC(1) EDGE_ACC(2) EDGE_ACC(3)
            j += 4;
        }
        for (; j < m; ++j) {
            EDGE_LOAD(0)
            EDGE_ACC(0)
        }
#undef EDGE_LOAD
#undef EDGE_ACC
    }

    // root + bias + relu
    unsigned ur = y32[(size_t)n * YWD + (NREL * CH / 2) + lane];
    float o0 = a0 + lof(ur) + bias[lane * 2];
    float o1 = a1 + hif(ur) + bias[lane * 2 + 1];
    float2 ov;
    ov.x = fmaxf(o0, 0.f);
    ov.y = fmaxf(o1, 0.f);
    *(float2*)(out + (size_t)n * CH + lane * 2) = ov;
}

extern "C" void kernel_launch(void* const* d_in, const int* in_sizes, int n_in,
                              void* d_out, int out_size, void* d_ws, size_t ws_size,
                              hipStream_t stream)
{
    const float* x    = (const float*)d_in[0];
    const int*   ei   = (const int*)d_in[1];
    const int*   et   = (const int*)d_in[2];
    const float* W    = (const float*)d_in[3];
    const float* root = (const float*)d_in[4];
    const float* bias = (const float*)d_in[5];
    float*       out  = (float*)d_out;

    int N = in_sizes[0] / CH;
    int E = in_sizes[2];
    const int* src = ei;
    const int* dst = ei + E;

    int S  = N * NREL;
    int NB = (S + SCAN_CHUNK - 1) / SCAN_CHUNK;

    // workspace layout (~245 MB)
    unsigned short* y   = (unsigned short*)d_ws;              // N*1152 bf16
    unsigned short* Bt2 = y + (size_t)N * YW;                 // 1152*128 bf16
    int* hist     = (int*)(Bt2 + (size_t)YW * CH);            // S
    int* pad_offs = hist + S;                                 // S+1
    int* partials = pad_offs + S + 1;                         // 256
    int* perm     = partials + 256;                           // E
    int* ofs      = pad_offs + 1;                             // alias view

    hipMemsetAsync(hist, 0, (size_t)S * sizeof(int), stream);

    int egrid = (E + 255) / 256;
    bt2_kernel<<<(YW * CH + 255) / 256, 256, 0, stream>>>(W, root, Bt2);
    hist_kernel<<<egrid, 256, 0, stream>>>(dst, et, hist, E);
    scan1_kernel<<<NB, SCAN_THREADS, 0, stream>>>(hist, ofs, partials, S);
    scan2_kernel<<<1, SCAN_THREADS, 0, stream>>>(partials, NB);
    finalize_kernel<<<(S + 255) / 256, 256, 0, stream>>>(ofs, partials, pad_offs, S);
    fill_kernel<<<egrid, 256, 0, stream>>>(src, dst, et, ofs, perm, E);
    ygemm_kernel<<<(N + 127) / 128, 512, 0, stream>>>(x, Bt2, y, N);
    gather_kernel<<<(N + 3) / 4, 256, 0, stream>>>(y, perm, pad_offs, bias, out, N);
}

// Round 9
// 318.074 us; speedup vs baseline: 4.4880x; 1.0581x over previous
//
#include <hip/hip_runtime.h>

#define NREL 8
#define CH   128                 // IN_CH == HID == 128
#define YW   1152                // y row width: 8 rels + root, each 128
#define YWD  (YW / 2)            // y row width in dwords (576)
#define NCB  9                   // col-blocks of 128 in ygemm

#define SCAN_ITEMS   16
#define SCAN_THREADS 256
#define SCAN_CHUNK   (SCAN_ITEMS * SCAN_THREADS)   // 4096
#define SCAN_SHIFT   12

typedef short  short8v __attribute__((ext_vector_type(8)));
typedef float  f32x4   __attribute__((ext_vector_type(4)));

__device__ __forceinline__ unsigned short f2bf(float f) {
    union { float f; unsigned u; } v; v.f = f;
    return (unsigned short)((v.u + 0x7FFFu + ((v.u >> 16) & 1u)) >> 16);
}
__device__ __forceinline__ float lof(unsigned u) {
    union { unsigned u; float f; } v; v.u = u << 16; return v.f;
}
__device__ __forceinline__ float hif(unsigned u) {
    union { unsigned u; float f; } v; v.u = u & 0xFFFF0000u; return v.f;
}
__device__ __forceinline__ void gload_lds16(const void* g, void* l) {
    __builtin_amdgcn_global_load_lds(
        (const __attribute__((address_space(1))) unsigned int*)g,
        (__attribute__((address_space(3))) unsigned int*)l, 16, 0, 0);
}

// ---------------------------------------------------------------------------
// 0. Bt2[rc][k] = bf16( Wcat[k][rc] ); rc = r*128+c
// ---------------------------------------------------------------------------
__global__ __launch_bounds__(256) void bt2_kernel(
    const float* __restrict__ W, const float* __restrict__ root,
    unsigned short* __restrict__ Bt2)
{
    int idx = blockIdx.x * blockDim.x + threadIdx.x;   // rc*128 + k
    if (idx >= YW * CH) return;
    int rc = idx >> 7, k = idx & 127;
    int r = rc >> 7, c = rc & 127;
    float v = (r < NREL) ? W[(size_t)(r * CH + k) * CH + c]
                         : root[(size_t)k * CH + c];
    Bt2[idx] = f2bf(v);
}

// ---------------------------------------------------------------------------
// 1. histogram over node-major segments seg = dst*8 + et
// ---------------------------------------------------------------------------
__global__ __launch_bounds__(256) void hist_kernel(
    const int* __restrict__ dst, const int* __restrict__ et,
    int* __restrict__ hist, int E)
{
    int e = blockIdx.x * blockDim.x + threadIdx.x;
    if (e < E) atomicAdd(&hist[dst[e] * NREL + et[e]], 1);
}

// ---------------------------------------------------------------------------
// 2a/2b. two-level exclusive scan (scan1 writes ofs = pad_offs+1)
// ---------------------------------------------------------------------------
__global__ __launch_bounds__(SCAN_THREADS) void scan1_kernel(
    const int* __restrict__ hist, int* __restrict__ ofs,
    int* __restrict__ partials, int S)
{
    __shared__ int lds[SCAN_THREADS];
    int t = threadIdx.x;
    int base = blockIdx.x * SCAN_CHUNK + t * SCAN_ITEMS;
    int v[SCAN_ITEMS];
    int s = 0;
#pragma unroll
    for (int j = 0; j < SCAN_ITEMS; j++) {
        int idx = base + j;
        int h = (idx < S) ? hist[idx] : 0;
        v[j] = s; s += h;
    }
    int run = s;
    lds[t] = run; __syncthreads();
    for (int off = 1; off < SCAN_THREADS; off <<= 1) {
        int y = (t >= off) ? lds[t - off] : 0;
        __syncthreads();
        run += y; lds[t] = run; __syncthreads();
    }
    int tb = run - s;
    if (t == SCAN_THREADS - 1) partials[blockIdx.x] = run;
#pragma unroll
    for (int j = 0; j < SCAN_ITEMS; j++) {
        int idx = base + j;
        if (idx < S) ofs[idx] = tb + v[j];
    }
}

__global__ __launch_bounds__(SCAN_THREADS) void scan2_kernel(
    int* __restrict__ partials, int NB)
{
    __shared__ int lds[SCAN_THREADS];
    int t = threadIdx.x;
    int s = (t < NB) ? partials[t] : 0;
    int run = s;
    lds[t] = run; __syncthreads();
    for (int off = 1; off < SCAN_THREADS; off <<= 1) {
        int y = (t >= off) ? lds[t - off] : 0;
        __syncthreads();
        run += y; lds[t] = run; __syncthreads();
    }
    if (t < NB) partials[t] = run - s;
}

// ---------------------------------------------------------------------------
// 2c. ofs -> absolute; pad_offs[0] = 0
// ---------------------------------------------------------------------------
__global__ __launch_bounds__(256) void finalize_kernel(
    int* __restrict__ ofs, const int* __restrict__ partials,
    int* __restrict__ pad_offs, int S)
{
    int i = blockIdx.x * blockDim.x + threadIdx.x;
    if (i < S) ofs[i] += partials[i >> SCAN_SHIFT];
    if (i == 0) pad_offs[0] = 0;
}

// ---------------------------------------------------------------------------
// 4. FUSED ygemm + fill.
//    Per block: (a) issue fill for a 2048-edge slice (4 edges/thread,
//    static unroll; atomics issued before A-staging so their latency hides
//    under it; perm writes after), (b) y[n][rc] GEMM tile as before.
//    Fill: pos = atomicAdd(&ofs[seg],1) (DESTRUCTIVE -> ofs becomes ends).
// ---------------------------------------------------------------------------
__global__ __launch_bounds__(512) void ygemm_fill_kernel(
    const float* __restrict__ x,
    const unsigned short* __restrict__ Bt2,   // [1152][128]
    unsigned short* __restrict__ y,           // [N][1152]
    int N,
    const int* __restrict__ src, const int* __restrict__ dst,
    const int* __restrict__ et, int* __restrict__ ofs,
    int* __restrict__ perm, int E, int epb)
{
    __shared__ __align__(16) unsigned short As[128 * 128];  // 32 KB
    __shared__ __align__(16) unsigned short Bs[128 * 128];  // 32 KB

    int tid  = threadIdx.x;
    int lane = tid & 63;
    int wid  = tid >> 6;
    int wm   = wid >> 2;       // 0..1
    int wn   = wid & 3;        // 0..3
    int r15  = lane & 15;
    int kg   = lane >> 4;      // 0..3
    int n0   = blockIdx.x * 128;

    // ---- fill phase 1: issue edge loads + atomics (4 edges/thread) ----
    int eb   = blockIdx.x * epb;
    int elim = eb + epb; if (elim > E) elim = E;
    int p0 = -1, p1 = -1, p2 = -1, p3 = -1;
    int s0 = 0, s1 = 0, s2 = 0, s3 = 0;
    {
        int e0 = eb + tid;
        int e1 = e0 + 512, e2 = e1 + 512, e3 = e2 + 512;
        if (e0 < elim) { s0 = src[e0]; p0 = atomicAdd(&ofs[dst[e0] * NREL + et[e0]], 1); }
        if (e1 < elim) { s1 = src[e1]; p1 = atomicAdd(&ofs[dst[e1] * NREL + et[e1]], 1); }
        if (e2 < elim) { s2 = src[e2]; p2 = atomicAdd(&ofs[dst[e2] * NREL + et[e2]], 1); }
        if (e3 < elim) { s3 = src[e3]; p3 = atomicAdd(&ofs[dst[e3] * NREL + et[e3]], 1); }
    }

    // ---- stage A once (overlaps the atomic round-trips) ----
    {
        int row = tid >> 2;
        int kq  = tid & 3;
        int gn  = n0 + row; if (gn >= N) gn = N - 1;
        const float* xp = x + (size_t)gn * CH + kq * 32;
#pragma unroll
        for (int s8 = 0; s8 < 4; ++s8) {
            float4 f0 = *(const float4*)(xp + s8 * 8);
            float4 f1 = *(const float4*)(xp + s8 * 8 + 4);
            uint4 v;
            v.x = f2bf(f0.x) | ((unsigned)f2bf(f0.y) << 16);
            v.y = f2bf(f0.z) | ((unsigned)f2bf(f0.w) << 16);
            v.z = f2bf(f1.x) | ((unsigned)f2bf(f1.y) << 16);
            v.w = f2bf(f1.z) | ((unsigned)f2bf(f1.w) << 16);
            int slot = kq * 4 + s8;
            int phys = slot ^ (row & 15);
            *(uint4*)&As[row * 128 + phys * 8] = v;
        }
    }

    // ---- fill phase 2: scatter perm (atomic results have landed) ----
    if (p0 >= 0) perm[p0] = s0;
    if (p1 >= 0) perm[p1] = s1;
    if (p2 >= 0) perm[p2] = s2;
    if (p3 >= 0) perm[p3] = s3;

    for (int cb = 0; cb < NCB; ++cb) {
#pragma unroll
        for (int i = 0; i < 4; ++i) {
            int chunk = wid * 4 + i;
            int col   = chunk * 4 + (lane >> 4);
            int slog  = (lane & 15) ^ (col & 15);
            const char* srcp = (const char*)(Bt2 + (size_t)(cb * CH + col) * CH + slog * 8);
            gload_lds16(srcp, &Bs[chunk * 512]);
        }
        __syncthreads();

        f32x4 acc[4][2];
#pragma unroll
        for (int i = 0; i < 4; i++)
#pragma unroll
            for (int j = 0; j < 2; j++)
                acc[i][j] = f32x4{0.f, 0.f, 0.f, 0.f};

#pragma unroll
        for (int ks = 0; ks < 4; ++ks) {
            short8v a[4], b[2];
#pragma unroll
            for (int mr = 0; mr < 4; ++mr) {
                int row  = wm * 64 + mr * 16 + r15;
                int phys = (ks * 4 + kg) ^ (row & 15);
                a[mr] = *(const short8v*)&As[row * 128 + phys * 8];
            }
#pragma unroll
            for (int nc = 0; nc < 2; ++nc) {
                int col  = wn * 32 + nc * 16 + r15;
                int phys = (ks * 4 + kg) ^ (col & 15);
                b[nc] = *(const short8v*)&Bs[col * 128 + phys * 8];
            }
#pragma unroll
            for (int mr = 0; mr < 4; ++mr)
#pragma unroll
                for (int nc = 0; nc < 2; ++nc)
                    acc[mr][nc] = __builtin_amdgcn_mfma_f32_16x16x32_bf16(
                        a[mr], b[nc], acc[mr][nc], 0, 0, 0);
        }

#pragma unroll
        for (int mr = 0; mr < 4; ++mr) {
#pragma unroll
            for (int reg = 0; reg < 4; ++reg) {
                int gr = n0 + wm * 64 + mr * 16 + kg * 4 + reg;
                if (gr >= N) continue;
#pragma unroll
                for (int nc = 0; nc < 2; ++nc) {
                    int gc = cb * CH + wn * 32 + nc * 16 + r15;
                    y[(size_t)gr * YW + gc] = f2bf(acc[mr][nc][reg]);
                }
            }
        }
        __syncthreads();
    }
}

// ---------------------------------------------------------------------------
// 5. gather: out[n] = relu( sum_e w_e * y[src_e*9+rel_e] + y_root[n] + bias )
//    One wave per node; rel/weight derived from boundaries; unroll-16 MLP.
// ---------------------------------------------------------------------------
__global__ __launch_bounds__(256) void gather_kernel(
    const unsigned short* __restrict__ y,
    const int* __restrict__ perm,
    const int* __restrict__ pad_offs,
    const float* __restrict__ bias,
    float* __restrict__ out, int N)
{
    int wid  = threadIdx.x >> 6;
    int lane = threadIdx.x & 63;
    int n    = blockIdx.x * 4 + wid;
    if (n >= N) return;

    const int* bp = pad_offs + n * NREL;
    int b0 = bp[0], b1 = bp[1], b2 = bp[2], b3 = bp[3], b4 = bp[4];
    int b5 = bp[5], b6 = bp[6], b7 = bp[7], b8 = bp[8];

    const unsigned* y32 = (const unsigned*)y;
    float a0 = 0.f, a1 = 0.f;

    for (int blk = b0; blk < b8; blk += 64) {
        int m = b8 - blk; if (m > 64) m = 64;
        int   pv = 0;
        float wv = 0.f;
        if (lane < m) {
            int g   = blk + lane;
            int s   = perm[g];
            int c1 = g >= b1, c2 = g >= b2, c3 = g >= b3, c4 = g >= b4;
            int c5 = g >= b5, c6 = g >= b6, c7 = g >= b7;
            int r  = c1 + c2 + c3 + c4 + c5 + c6 + c7;
            int br  = b0;
            br  = c1 ? b1 : br;  br  = c2 ? b2 : br;  br  = c3 ? b3 : br;
            br  = c4 ? b4 : br;  br  = c5 ? b5 : br;  br  = c6 ? b6 : br;
            br  = c7 ? b7 : br;
            int br1 = b1;
            br1 = c1 ? b2 : br1; br1 = c2 ? b3 : br1; br1 = c3 ? b4 : br1;
            br1 = c4 ? b5 : br1; br1 = c5 ? b6 : br1; br1 = c6 ? b7 : br1;
            br1 = c7 ? b8 : br1;
            pv = s * 9 + r;
            wv = 1.0f / (float)(br1 - br);
        }

        int j = 0;
#define EDGE_LOAD(K) \
            int   p##K = __shfl(pv, j + K);                     \
            float w##K = __shfl(wv, j + K);                     \
            unsigned u##K = y32[(size_t)p##K * 64 + lane];
#define EDGE_ACC(K) \
            a0 += w##K * lof(u##K); a1 += w##K * hif(u##K);

        for (; j + 16 <= m; j += 16) {
            EDGE_LOAD(0) EDGE_LOAD(1) EDGE_LOAD(2)  EDGE_LOAD(3)
            EDGE_LOAD(4) EDGE_LOAD(5) EDGE_LOAD(6)  EDGE_LOAD(7)
            EDGE_LOAD(8) EDGE_LOAD(9) EDGE_LOAD(10) EDGE_LOAD(11)
            EDGE_LOAD(12) EDGE_LOAD(13) EDGE_LOAD(14) EDGE_LOAD(15)
            EDGE_ACC(0)  EDGE_ACC(1)  EDGE_ACC(2)  EDGE_ACC(3)
            EDGE_ACC(4)  EDGE_ACC(5)  EDGE_ACC(6)  EDGE_ACC(7)
            EDGE_ACC(8)  EDGE_ACC(9)  EDGE_ACC(10) EDGE_ACC(11)
            EDGE_ACC(12) EDGE_ACC(13) EDGE_ACC(14) EDGE_ACC(15)
        }
        if (j + 8 <= m) {
            EDGE_LOAD(0) EDGE_LOAD(1) EDGE_LOAD(2) EDGE_LOAD(3)
            EDGE_LOAD(4) EDGE_LOAD(5) EDGE_LOAD(6) EDGE_LOAD(7)
            EDGE_ACC(0) EDGE_ACC(1) EDGE_ACC(2) EDGE_ACC(3)
            EDGE_ACC(4) EDGE_ACC(5) EDGE_ACC(6) EDGE_ACC(7)
            j += 8;
        }
        if (j + 4 <= m) {
            EDGE_LOAD(0) EDGE_LOAD(1) EDGE_LOAD(2) EDGE_LOAD(3)
            EDGE_ACC(0) EDGE_ACC(1) EDGE_ACC(2) EDGE_ACC(3)
            j += 4;
        }
        for (; j < m; ++j) {
            EDGE_LOAD(0)
            EDGE_ACC(0)
        }
#undef EDGE_LOAD
#undef EDGE_ACC
    }

    // root + bias + relu
    unsigned ur = y32[(size_t)n * YWD + (NREL * CH / 2) + lane];
    float o0 = a0 + lof(ur) + bias[lane * 2];
    float o1 = a1 + hif(ur) + bias[lane * 2 + 1];
    float2 ov;
    ov.x = fmaxf(o0, 0.f);
    ov.y = fmaxf(o1, 0.f);
    *(float2*)(out + (size_t)n * CH + lane * 2) = ov;
}

extern "C" void kernel_launch(void* const* d_in, const int* in_sizes, int n_in,
                              void* d_out, int out_size, void* d_ws, size_t ws_size,
                              hipStream_t stream)
{
    const float* x    = (const float*)d_in[0];
    const int*   ei   = (const int*)d_in[1];
    const int*   et   = (const int*)d_in[2];
    const float* W    = (const float*)d_in[3];
    const float* root = (const float*)d_in[4];
    const float* bias = (const float*)d_in[5];
    float*       out  = (float*)d_out;

    int N = in_sizes[0] / CH;
    int E = in_sizes[2];
    const int* src = ei;
    const int* dst = ei + E;

    int S  = N * NREL;
    int NB = (S + SCAN_CHUNK - 1) / SCAN_CHUNK;

    // workspace layout (~245 MB)
    unsigned short* y   = (unsigned short*)d_ws;              // N*1152 bf16
    unsigned short* Bt2 = y + (size_t)N * YW;                 // 1152*128 bf16
    int* hist     = (int*)(Bt2 + (size_t)YW * CH);            // S
    int* pad_offs = hist + S;                                 // S+1
    int* partials = pad_offs + S + 1;                         // 256
    int* perm     = partials + 256;                           // E
    int* ofs      = pad_offs + 1;                             // alias view

    hipMemsetAsync(hist, 0, (size_t)S * sizeof(int), stream);

    int egrid = (E + 255) / 256;
    int G     = (N + 127) / 128;                              // ygemm grid
    int epb   = ((E + G - 1) / G + 511) & ~511;               // edges per block

    bt2_kernel<<<(YW * CH + 255) / 256, 256, 0, stream>>>(W, root, Bt2);
    hist_kernel<<<egrid, 256, 0, stream>>>(dst, et, hist, E);
    scan1_kernel<<<NB, SCAN_THREADS, 0, stream>>>(hist, ofs, partials, S);
    scan2_kernel<<<1, SCAN_THREADS, 0, stream>>>(partials, NB);
    finalize_kernel<<<(S + 255) / 256, 256, 0, stream>>>(ofs, partials, pad_offs, S);
    ygemm_fill_kernel<<<G, 512, 0, stream>>>(x, Bt2, y, N,
                                             src, dst, et, ofs, perm, E, epb);
    gather_kernel<<<(N + 3) / 4, 256, 0, stream>>>(y, perm, pad_offs, bias, out, N);
}

// Round 10
// 313.328 us; speedup vs baseline: 4.5560x; 1.0151x over previous
//
#include <hip/hip_runtime.h>

#define NREL 8
#define CH   128                 // IN_CH == HID == 128
#define YW   1152                // y row width: 8 rels + root, each 128
#define YWD  (YW / 2)            // y row width in dwords (576)
#define NCB2 18                  // 64-col chunks in ygemm

#define SCAN_THREADS 256
#define NSC_ITEMS    4           // nodes per thread in scan1
#define NSC_CHUNK    1024        // nodes per block
#define NSC_SHIFT    10

typedef short  short8v __attribute__((ext_vector_type(8)));
typedef float  f32x4   __attribute__((ext_vector_type(4)));

__device__ __forceinline__ unsigned short f2bf(float f) {
    union { float f; unsigned u; } v; v.f = f;
    return (unsigned short)((v.u + 0x7FFFu + ((v.u >> 16) & 1u)) >> 16);
}
__device__ __forceinline__ float lof(unsigned u) {
    union { unsigned u; float f; } v; v.u = u << 16; return v.f;
}
__device__ __forceinline__ float hif(unsigned u) {
    union { unsigned u; float f; } v; v.u = u & 0xFFFF0000u; return v.f;
}
__device__ __forceinline__ void gload_lds16(const void* g, void* l) {
    __builtin_amdgcn_global_load_lds(
        (const __attribute__((address_space(1))) unsigned int*)g,
        (__attribute__((address_space(3))) unsigned int*)l, 16, 0, 0);
}

// ---------------------------------------------------------------------------
// 0. Bt2[rc][k] = bf16( Wcat[k][rc] ); rc = r*128+c
// ---------------------------------------------------------------------------
__global__ __launch_bounds__(256) void bt2_kernel(
    const float* __restrict__ W, const float* __restrict__ root,
    unsigned short* __restrict__ Bt2)
{
    int idx = blockIdx.x * blockDim.x + threadIdx.x;   // rc*128 + k
    if (idx >= YW * CH) return;
    int rc = idx >> 7, k = idx & 127;
    int r = rc >> 7, c = rc & 127;
    float v = (r < NREL) ? W[(size_t)(r * CH + k) * CH + c]
                         : root[(size_t)k * CH + c];
    Bt2[idx] = f2bf(v);
}

// ---------------------------------------------------------------------------
// 1. histogram over seg = dst*8 + et (kept: gather reads counts for weights)
// ---------------------------------------------------------------------------
__global__ __launch_bounds__(256) void hist_kernel(
    const int* __restrict__ dst, const int* __restrict__ et,
    int* __restrict__ hist, int E)
{
    int e = blockIdx.x * blockDim.x + threadIdx.x;
    if (e < E) atomicAdd(&hist[dst[e] * NREL + et[e]], 1);
}

// ---------------------------------------------------------------------------
// 2a. node-level scan: item n = degree(n) = sum of 8 hist entries.
//     Writes local-prefixed starts into nofs[n] (= pad_noffs+1).
// ---------------------------------------------------------------------------
__global__ __launch_bounds__(SCAN_THREADS) void scan1_kernel(
    const int* __restrict__ hist, int* __restrict__ nofs,
    int* __restrict__ partials, int N)
{
    __shared__ int lds[SCAN_THREADS];
    int t = threadIdx.x;
    int base = blockIdx.x * NSC_CHUNK + t * NSC_ITEMS;
    int v[NSC_ITEMS];
    int s = 0;
#pragma unroll
    for (int j = 0; j < NSC_ITEMS; j++) {
        int n = base + j;
        int deg = 0;
        if (n < N) {
            int4 a = *(const int4*)(hist + (size_t)n * NREL);
            int4 b = *(const int4*)(hist + (size_t)n * NREL + 4);
            deg = a.x + a.y + a.z + a.w + b.x + b.y + b.z + b.w;
        }
        v[j] = s; s += deg;
    }
    int run = s;
    lds[t] = run; __syncthreads();
    for (int off = 1; off < SCAN_THREADS; off <<= 1) {
        int y = (t >= off) ? lds[t - off] : 0;
        __syncthreads();
        run += y; lds[t] = run; __syncthreads();
    }
    int tb = run - s;
    if (t == SCAN_THREADS - 1) partials[blockIdx.x] = run;
#pragma unroll
    for (int j = 0; j < NSC_ITEMS; j++) {
        int n = base + j;
        if (n < N) nofs[n] = tb + v[j];
    }
}

__global__ __launch_bounds__(SCAN_THREADS) void scan2_kernel(
    int* __restrict__ partials, int NB)
{
    __shared__ int lds[SCAN_THREADS];
    int t = threadIdx.x;
    int s = (t < NB) ? partials[t] : 0;
    int run = s;
    lds[t] = run; __syncthreads();
    for (int off = 1; off < SCAN_THREADS; off <<= 1) {
        int y = (t >= off) ? lds[t - off] : 0;
        __syncthreads();
        run += y; lds[t] = run; __syncthreads();
    }
    if (t < NB) partials[t] = run - s;
}

// ---------------------------------------------------------------------------
// 2c. nofs -> absolute; pad_noffs[0] = 0
// ---------------------------------------------------------------------------
__global__ __launch_bounds__(256) void finalize_kernel(
    int* __restrict__ nofs, const int* __restrict__ partials,
    int* __restrict__ pad_noffs, int N)
{
    int i = blockIdx.x * blockDim.x + threadIdx.x;
    if (i < N) nofs[i] += partials[i >> NSC_SHIFT];
    if (i == 0) pad_noffs[0] = 0;
}

// ---------------------------------------------------------------------------
// 4. FUSED ygemm + fill (node-level CSR).
//    fill: pos = atomicAdd(&nofs[dst],1) (destructive -> nofs = node ends);
//    perm[pos] = (src<<3)|rel.
//    GEMM: 128 rows x 1152 cols in 18 64-col chunks; LDS 48 KB -> 3 blk/CU.
// ---------------------------------------------------------------------------
__global__ __launch_bounds__(512, 6) void ygemm_fill_kernel(
    const float* __restrict__ x,
    const unsigned short* __restrict__ Bt2,   // [1152][128]
    unsigned short* __restrict__ y,           // [N][1152]
    int N,
    const int* __restrict__ src, const int* __restrict__ dst,
    const int* __restrict__ et, int* __restrict__ nofs,
    int* __restrict__ perm, int E, int epb)
{
    __shared__ __align__(16) unsigned short As[128 * 128];  // 32 KB
    __shared__ __align__(16) unsigned short Bs[64 * 128];   // 16 KB

    int tid  = threadIdx.x;
    int lane = tid & 63;
    int wid  = tid >> 6;
    int wm   = wid >> 2;       // 0..1 -> 64-row half
    int wn   = wid & 3;        // 0..3 -> 16-col slice
    int r15  = lane & 15;
    int kg   = lane >> 4;      // 0..3
    int n0   = blockIdx.x * 128;

    // ---- fill phase 1: issue edge loads + atomics (4 edges/thread) ----
    int eb   = blockIdx.x * epb;
    int elim = eb + epb; if (elim > E) elim = E;
    int p0 = -1, p1 = -1, p2 = -1, p3 = -1;
    int v0 = 0, v1 = 0, v2 = 0, v3 = 0;
    {
        int e0 = eb + tid;
        int e1 = e0 + 512, e2 = e1 + 512, e3 = e2 + 512;
        if (e0 < elim) { v0 = (src[e0] << 3) | et[e0]; p0 = atomicAdd(&nofs[dst[e0]], 1); }
        if (e1 < elim) { v1 = (src[e1] << 3) | et[e1]; p1 = atomicAdd(&nofs[dst[e1]], 1); }
        if (e2 < elim) { v2 = (src[e2] << 3) | et[e2]; p2 = atomicAdd(&nofs[dst[e2]], 1); }
        if (e3 < elim) { v3 = (src[e3] << 3) | et[e3]; p3 = atomicAdd(&nofs[dst[e3]], 1); }
    }

    // ---- stage A once (overlaps the atomic round-trips) ----
    {
        int row = tid >> 2;
        int kq  = tid & 3;
        int gn  = n0 + row; if (gn >= N) gn = N - 1;
        const float* xp = x + (size_t)gn * CH + kq * 32;
#pragma unroll
        for (int s8 = 0; s8 < 4; ++s8) {
            float4 f0 = *(const float4*)(xp + s8 * 8);
            float4 f1 = *(const float4*)(xp + s8 * 8 + 4);
            uint4 v;
            v.x = f2bf(f0.x) | ((unsigned)f2bf(f0.y) << 16);
            v.y = f2bf(f0.z) | ((unsigned)f2bf(f0.w) << 16);
            v.z = f2bf(f1.x) | ((unsigned)f2bf(f1.y) << 16);
            v.w = f2bf(f1.z) | ((unsigned)f2bf(f1.w) << 16);
            int slot = kq * 4 + s8;
            int phys = slot ^ (row & 15);
            *(uint4*)&As[row * 128 + phys * 8] = v;
        }
    }

    // ---- fill phase 2: scatter perm (atomic results have landed) ----
    if (p0 >= 0) perm[p0] = v0;
    if (p1 >= 0) perm[p1] = v1;
    if (p2 >= 0) perm[p2] = v2;
    if (p3 >= 0) perm[p3] = v3;

    for (int cb = 0; cb < NCB2; ++cb) {
        // ---- stage Bs: 64 cols x 128 k (16 x 1KB chunks, 2 per wave) ----
#pragma unroll
        for (int i = 0; i < 2; ++i) {
            int chunk = wid * 2 + i;              // 0..15
            int col   = chunk * 4 + (lane >> 4);  // 0..63
            int slot  = (lane & 15) ^ (col & 15);
            const char* srcp = (const char*)(Bt2 + (size_t)(cb * 64 + col) * CH + slot * 8);
            gload_lds16(srcp, &Bs[chunk * 512]);
        }
        __syncthreads();

        f32x4 acc[4];
#pragma unroll
        for (int i = 0; i < 4; i++) acc[i] = f32x4{0.f, 0.f, 0.f, 0.f};

#pragma unroll
        for (int ks = 0; ks < 4; ++ks) {
            short8v a[4], b;
#pragma unroll
            for (int mr = 0; mr < 4; ++mr) {
                int row  = wm * 64 + mr * 16 + r15;
                int phys = (ks * 4 + kg) ^ (row & 15);
                a[mr] = *(const short8v*)&As[row * 128 + phys * 8];
            }
            {
                int col  = wn * 16 + r15;
                int phys = (ks * 4 + kg) ^ (col & 15);
                b = *(const short8v*)&Bs[col * 128 + phys * 8];
            }
#pragma unroll
            for (int mr = 0; mr < 4; ++mr)
                acc[mr] = __builtin_amdgcn_mfma_f32_16x16x32_bf16(
                    a[mr], b, acc[mr], 0, 0, 0);
        }

        // ---- epilogue: C/D layout col = lane&15, row = (lane>>4)*4+reg ----
#pragma unroll
        for (int mr = 0; mr < 4; ++mr) {
#pragma unroll
            for (int reg = 0; reg < 4; ++reg) {
                int gr = n0 + wm * 64 + mr * 16 + kg * 4 + reg;
                if (gr >= N) continue;
                int gc = cb * 64 + wn * 16 + r15;
                y[(size_t)gr * YW + gc] = f2bf(acc[mr][reg]);
            }
        }
        __syncthreads();
    }
}

// ---------------------------------------------------------------------------
// 5. gather: out[n] = relu( sum_e w_e * y[(pv+(pv>>3))*128..] + y_root + bias )
//    One wave per node. Boundaries = pad_noffs[n], pad_noffs[n+1]; weights
//    from hist[n*8+rel] selected by 3-level cndmask; unroll-16 row loads.
// ---------------------------------------------------------------------------
__global__ __launch_bounds__(256) void gather_kernel(
    const unsigned short* __restrict__ y,
    const int* __restrict__ perm,
    const int* __restrict__ pad_noffs,
    const int* __restrict__ hist,
    const float* __restrict__ bias,
    float* __restrict__ out, int N)
{
    int wid  = threadIdx.x >> 6;
    int lane = threadIdx.x & 63;
    int n    = blockIdx.x * 4 + wid;
    if (n >= N) return;

    int beg = pad_noffs[n];
    int end = pad_noffs[n + 1];

    int4 h0 = *(const int4*)(hist + (size_t)n * NREL);
    int4 h1 = *(const int4*)(hist + (size_t)n * NREL + 4);
    float iw0 = 1.0f / (float)max(h0.x, 1);
    float iw1 = 1.0f / (float)max(h0.y, 1);
    float iw2 = 1.0f / (float)max(h0.z, 1);
    float iw3 = 1.0f / (float)max(h0.w, 1);
    float iw4 = 1.0f / (float)max(h1.x, 1);
    float iw5 = 1.0f / (float)max(h1.y, 1);
    float iw6 = 1.0f / (float)max(h1.z, 1);
    float iw7 = 1.0f / (float)max(h1.w, 1);

    const unsigned* y32 = (const unsigned*)y;
    float a0 = 0.f, a1 = 0.f;

    for (int blk = beg; blk < end; blk += 64) {
        int m = end - blk; if (m > 64) m = 64;
        int   rv = 0;
        float wv = 0.f;
        if (lane < m) {
            int pv  = perm[blk + lane];
            int rel = pv & 7;
            rv = pv + (pv >> 3);                  // = src*9 + rel
            float wa = (rel & 1) ? iw1 : iw0;
            float wb = (rel & 1) ? iw3 : iw2;
            float wc = (rel & 1) ? iw5 : iw4;
            float wd = (rel & 1) ? iw7 : iw6;
            float we_ = (rel & 2) ? wb : wa;
            float wf  = (rel & 2) ? wd : wc;
            wv = (rel & 4) ? wf : we_;
        }

        int j = 0;
#define EDGE_LOAD(K) \
            int   p##K = __shfl(rv, j + K);                     \
            float w##K = __shfl(wv, j + K);                     \
            unsigned u##K = y32[(size_t)p##K * 64 + lane];
#define EDGE_ACC(K) \
            a0 += w##K * lof(u##K); a1 += w##K * hif(u##K);

        for (; j + 16 <= m; j += 16) {
            EDGE_LOAD(0) EDGE_LOAD(1) EDGE_LOAD(2)  EDGE_LOAD(3)
            EDGE_LOAD(4) EDGE_LOAD(5) EDGE_LOAD(6)  EDGE_LOAD(7)
            EDGE_LOAD(8) EDGE_LOAD(9) EDGE_LOAD(10) EDGE_LOAD(11)
            EDGE_LOAD(12) EDGE_LOAD(13) EDGE_LOAD(14) EDGE_LOAD(15)
            EDGE_ACC(0)  EDGE_ACC(1)  EDGE_ACC(2)  EDGE_ACC(3)
            EDGE_ACC(4)  EDGE_ACC(5)  EDGE_ACC(6)  EDGE_ACC(7)
            EDGE_ACC(8)  EDGE_ACC(9)  EDGE_ACC(10) EDGE_ACC(11)
            EDGE_ACC(12) EDGE_ACC(13) EDGE_ACC(14) EDGE_ACC(15)
        }
        if (j + 8 <= m) {
            EDGE_LOAD(0) EDGE_LOAD(1) EDGE_LOAD(2) EDGE_LOAD(3)
            EDGE_LOAD(4) EDGE_LOAD(5) EDGE_LOAD(6) EDGE_LOAD(7)
            EDGE_ACC(0) EDGE_ACC(1) EDGE_ACC(2) EDGE_ACC(3)
            EDGE_ACC(4) EDGE_ACC(5) EDGE_ACC(6) EDGE_ACC(7)
            j += 8;
        }
        if (j + 4 <= m) {
            EDGE_LOAD(0) EDGE_LOAD(1) EDGE_LOAD(2) EDGE_LOAD(3)
            EDGE_ACC(0) EDGE_ACC(1) EDGE_ACC(2) EDGE_ACC(3)
            j += 4;
        }
        for (; j < m; ++j) {
            EDGE_LOAD(0)
            EDGE_ACC(0)
        }
#undef EDGE_LOAD
#undef EDGE_ACC
    }

    // root + bias + relu
    unsigned ur = y32[(size_t)n * YWD + (NREL * CH / 2) + lane];
    float o0 = a0 + lof(ur) + bias[lane * 2];
    float o1 = a1 + hif(ur) + bias[lane * 2 + 1];
    float2 ov;
    ov.x = fmaxf(o0, 0.f);
    ov.y = fmaxf(o1, 0.f);
    *(float2*)(out + (size_t)n * CH + lane * 2) = ov;
}

extern "C" void kernel_launch(void* const* d_in, const int* in_sizes, int n_in,
                              void* d_out, int out_size, void* d_ws, size_t ws_size,
                              hipStream_t stream)
{
    const float* x    = (const float*)d_in[0];
    const int*   ei   = (const int*)d_in[1];
    const int*   et   = (const int*)d_in[2];
    const float* W    = (const float*)d_in[3];
    const float* root = (const float*)d_in[4];
    const float* bias = (const float*)d_in[5];
    float*       out  = (float*)d_out;

    int N = in_sizes[0] / CH;
    int E = in_sizes[2];
    const int* src = ei;
    const int* dst = ei + E;

    int S   = N * NREL;
    int NBn = (N + NSC_CHUNK - 1) / NSC_CHUNK;

    // workspace layout (~241 MB)
    unsigned short* y   = (unsigned short*)d_ws;              // N*1152 bf16
    unsigned short* Bt2 = y + (size_t)N * YW;                 // 1152*128 bf16
    int* hist      = (int*)(Bt2 + (size_t)YW * CH);           // S (persists!)
    int* pad_noffs = hist + S;                                // N+1
    int* partials  = pad_noffs + N + 1;                       // 256
    int* perm      = partials + 256;                          // E
    int* nofs      = pad_noffs + 1;                           // alias view

    hipMemsetAsync(hist, 0, (size_t)S * sizeof(int), stream);

    int egrid = (E + 255) / 256;
    int G     = (N + 127) / 128;                              // ygemm grid
    int epb   = ((E + G - 1) / G + 2047) & ~2047;             // edges per block

    bt2_kernel<<<(YW * CH + 255) / 256, 256, 0, stream>>>(W, root, Bt2);
    hist_kernel<<<egrid, 256, 0, stream>>>(dst, et, hist, E);
    scan1_kernel<<<NBn, SCAN_THREADS, 0, stream>>>(hist, nofs, partials, N);
    scan2_kernel<<<1, SCAN_THREADS, 0, stream>>>(partials, NBn);
    finalize_kernel<<<(N + 255) / 256, 256, 0, stream>>>(nofs, partials, pad_noffs, N);
    ygemm_fill_kernel<<<G, 512, 0, stream>>>(x, Bt2, y, N,
                                             src, dst, et, nofs, perm, E, epb);
    gather_kernel<<<(N + 3) / 4, 256, 0, stream>>>(y, perm, pad_noffs, hist, bias, out, N);
}

// Round 11
// 282.489 us; speedup vs baseline: 5.0533x; 1.1092x over previous
//
#include <hip/hip_runtime.h>

#define NREL 8
#define CH   128                 // IN_CH == HID == 128
#define YW   1152                // y row width: 8 rels + root, each 128
#define YWD  (YW / 2)            // y row width in dwords (576)
#define NCB2 18                  // 64-col chunks in ygemm

#define SCAN_ITEMS   16
#define SCAN_THREADS 256
#define SCAN_CHUNK   (SCAN_ITEMS * SCAN_THREADS)   // 4096
#define SCAN_SHIFT   12

typedef short  short8v __attribute__((ext_vector_type(8)));
typedef float  f32x4   __attribute__((ext_vector_type(4)));

__device__ __forceinline__ unsigned short f2bf(float f) {
    union { float f; unsigned u; } v; v.f = f;
    return (unsigned short)((v.u + 0x7FFFu + ((v.u >> 16) & 1u)) >> 16);
}
__device__ __forceinline__ float lof(unsigned u) {
    union { unsigned u; float f; } v; v.u = u << 16; return v.f;
}
__device__ __forceinline__ float hif(unsigned u) {
    union { unsigned u; float f; } v; v.u = u & 0xFFFF0000u; return v.f;
}
__device__ __forceinline__ void gload_lds16(const void* g, void* l) {
    __builtin_amdgcn_global_load_lds(
        (const __attribute__((address_space(1))) unsigned int*)g,
        (__attribute__((address_space(3))) unsigned int*)l, 16, 0, 0);
}

// ---------------------------------------------------------------------------
// 0. Bt2[rc][k] = bf16( Wcat[k][rc] ); rc = r*128+c
// ---------------------------------------------------------------------------
__global__ __launch_bounds__(256) void bt2_kernel(
    const float* __restrict__ W, const float* __restrict__ root,
    unsigned short* __restrict__ Bt2)
{
    int idx = blockIdx.x * blockDim.x + threadIdx.x;   // rc*128 + k
    if (idx >= YW * CH) return;
    int rc = idx >> 7, k = idx & 127;
    int r = rc >> 7, c = rc & 127;
    float v = (r < NREL) ? W[(size_t)(r * CH + k) * CH + c]
                         : root[(size_t)k * CH + c];
    Bt2[idx] = f2bf(v);
}

// ---------------------------------------------------------------------------
// 1. hist + rank: rank[e] = old count of segment (dst*8+et).
//    Return value written COALESCED by e -> atomic latency is TLP-hidden.
// ---------------------------------------------------------------------------
__global__ __launch_bounds__(256) void hist_rank_kernel(
    const int* __restrict__ dst, const int* __restrict__ et,
    int* __restrict__ hist, int* __restrict__ rank, int E)
{
    int e = blockIdx.x * blockDim.x + threadIdx.x;
    if (e < E) rank[e] = atomicAdd(&hist[dst[e] * NREL + et[e]], 1);
}

// ---------------------------------------------------------------------------
// 2a/2b. two-level exclusive scan over S segments -> pad_offs[i] = seg start
// ---------------------------------------------------------------------------
__global__ __launch_bounds__(SCAN_THREADS) void scan1_kernel(
    const int* __restrict__ hist, int* __restrict__ pad_offs,
    int* __restrict__ partials, int S)
{
    __shared__ int lds[SCAN_THREADS];
    int t = threadIdx.x;
    int base = blockIdx.x * SCAN_CHUNK + t * SCAN_ITEMS;
    int v[SCAN_ITEMS];
    int s = 0;
#pragma unroll
    for (int j = 0; j < SCAN_ITEMS; j++) {
        int idx = base + j;
        int h = (idx < S) ? hist[idx] : 0;
        v[j] = s; s += h;
    }
    int run = s;
    lds[t] = run; __syncthreads();
    for (int off = 1; off < SCAN_THREADS; off <<= 1) {
        int y = (t >= off) ? lds[t - off] : 0;
        __syncthreads();
        run += y; lds[t] = run; __syncthreads();
    }
    int tb = run - s;
    if (t == SCAN_THREADS - 1) partials[blockIdx.x] = run;
#pragma unroll
    for (int j = 0; j < SCAN_ITEMS; j++) {
        int idx = base + j;
        if (idx < S) pad_offs[idx] = tb + v[j];
    }
}

__global__ __launch_bounds__(SCAN_THREADS) void scan2_kernel(
    int* __restrict__ partials, int NB)
{
    __shared__ int lds[SCAN_THREADS];
    int t = threadIdx.x;
    int s = (t < NB) ? partials[t] : 0;
    int run = s;
    lds[t] = run; __syncthreads();
    for (int off = 1; off < SCAN_THREADS; off <<= 1) {
        int y = (t >= off) ? lds[t - off] : 0;
        __syncthreads();
        run += y; lds[t] = run; __syncthreads();
    }
    if (t < NB) partials[t] = run - s;
}

// ---------------------------------------------------------------------------
// 2c. pad_offs -> absolute; sentinel pad_offs[S] = E
// ---------------------------------------------------------------------------
__global__ __launch_bounds__(256) void finalize_kernel(
    int* __restrict__ pad_offs, const int* __restrict__ partials, int S, int E)
{
    int i = blockIdx.x * blockDim.x + threadIdx.x;
    if (i < S)       pad_offs[i] += partials[i >> SCAN_SHIFT];
    else if (i == S) pad_offs[i] = E;
}

// ---------------------------------------------------------------------------
// 4. FUSED ygemm + scatter-only fill (NO atomics, NO return deps).
//    Prologue: coalesced edge loads + 4 independent offs reads ->
//    pos = pad_offs[seg] + rank[e]. Scatters spread at cb=1..4, placed
//    right after the barrier so each drains under a full MFMA phase.
// ---------------------------------------------------------------------------
__global__ __launch_bounds__(512, 6) void ygemm_fill_kernel(
    const float* __restrict__ x,
    const unsigned short* __restrict__ Bt2,   // [1152][128]
    unsigned short* __restrict__ y,           // [N][1152]
    int N,
    const int* __restrict__ src, const int* __restrict__ dst,
    const int* __restrict__ et, const int* __restrict__ rank,
    const int* __restrict__ pad_offs,
    int* __restrict__ perm, int E, int epb)
{
    __shared__ __align__(16) unsigned short As[128 * 128];  // 32 KB
    __shared__ __align__(16) unsigned short Bs[64 * 128];   // 16 KB

    int tid  = threadIdx.x;
    int lane = tid & 63;
    int wid  = tid >> 6;
    int wm   = wid >> 2;       // 0..1 -> 64-row half
    int wn   = wid & 3;        // 0..3 -> 16-col slice
    int r15  = lane & 15;
    int kg   = lane >> 4;      // 0..3
    int n0   = blockIdx.x * 128;

    // ---- fill prologue: compute positions (no atomics) ----
    int eb   = blockIdx.x * epb;
    int elim = eb + epb; if (elim > E) elim = E;
    int p0 = -1, p1 = -1, p2 = -1, p3 = -1;
    int v0 = 0, v1 = 0, v2 = 0, v3 = 0;
    {
        int e0 = eb + tid;
        int e1 = e0 + 512, e2 = e1 + 512, e3 = e2 + 512;
        if (e0 < elim) { int t0 = et[e0]; v0 = (src[e0] << 3) | t0;
                         p0 = pad_offs[dst[e0] * NREL + t0] + rank[e0]; }
        if (e1 < elim) { int t1 = et[e1]; v1 = (src[e1] << 3) | t1;
                         p1 = pad_offs[dst[e1] * NREL + t1] + rank[e1]; }
        if (e2 < elim) { int t2 = et[e2]; v2 = (src[e2] << 3) | t2;
                         p2 = pad_offs[dst[e2] * NREL + t2] + rank[e2]; }
        if (e3 < elim) { int t3 = et[e3]; v3 = (src[e3] << 3) | t3;
                         p3 = pad_offs[dst[e3] * NREL + t3] + rank[e3]; }
    }

    // ---- stage A once ----
    {
        int row = tid >> 2;
        int kq  = tid & 3;
        int gn  = n0 + row; if (gn >= N) gn = N - 1;
        const float* xp = x + (size_t)gn * CH + kq * 32;
#pragma unroll
        for (int s8 = 0; s8 < 4; ++s8) {
            float4 f0 = *(const float4*)(xp + s8 * 8);
            float4 f1 = *(const float4*)(xp + s8 * 8 + 4);
            uint4 v;
            v.x = f2bf(f0.x) | ((unsigned)f2bf(f0.y) << 16);
            v.y = f2bf(f0.z) | ((unsigned)f2bf(f0.w) << 16);
            v.z = f2bf(f1.x) | ((unsigned)f2bf(f1.y) << 16);
            v.w = f2bf(f1.z) | ((unsigned)f2bf(f1.w) << 16);
            int slot = kq * 4 + s8;
            int phys = slot ^ (row & 15);
            *(uint4*)&As[row * 128 + phys * 8] = v;
        }
    }

    for (int cb = 0; cb < NCB2; ++cb) {
        // ---- stage Bs: 64 cols x 128 k (16 x 1KB chunks, 2 per wave) ----
#pragma unroll
        for (int i = 0; i < 2; ++i) {
            int chunk = wid * 2 + i;              // 0..15
            int col   = chunk * 4 + (lane >> 4);  // 0..63
            int slot  = (lane & 15) ^ (col & 15);
            const char* srcp = (const char*)(Bt2 + (size_t)(cb * 64 + col) * CH + slot * 8);
            gload_lds16(srcp, &Bs[chunk * 512]);
        }
        __syncthreads();

        // ---- spread perm scatter: one store per early iteration, placed
        //      after the barrier -> a full MFMA phase to drain ----
        if      (cb == 1) { if (p0 >= 0) perm[p0] = v0; }
        else if (cb == 2) { if (p1 >= 0) perm[p1] = v1; }
        else if (cb == 3) { if (p2 >= 0) perm[p2] = v2; }
        else if (cb == 4) { if (p3 >= 0) perm[p3] = v3; }

        f32x4 acc[4];
#pragma unroll
        for (int i = 0; i < 4; i++) acc[i] = f32x4{0.f, 0.f, 0.f, 0.f};

#pragma unroll
        for (int ks = 0; ks < 4; ++ks) {
            short8v a[4], b;
#pragma unroll
            for (int mr = 0; mr < 4; ++mr) {
                int row  = wm * 64 + mr * 16 + r15;
                int phys = (ks * 4 + kg) ^ (row & 15);
                a[mr] = *(const short8v*)&As[row * 128 + phys * 8];
            }
            {
                int col  = wn * 16 + r15;
                int phys = (ks * 4 + kg) ^ (col & 15);
                b = *(const short8v*)&Bs[col * 128 + phys * 8];
            }
#pragma unroll
            for (int mr = 0; mr < 4; ++mr)
                acc[mr] = __builtin_amdgcn_mfma_f32_16x16x32_bf16(
                    a[mr], b, acc[mr], 0, 0, 0);
        }

        // ---- epilogue: C/D layout col = lane&15, row = (lane>>4)*4+reg ----
#pragma unroll
        for (int mr = 0; mr < 4; ++mr) {
#pragma unroll
            for (int reg = 0; reg < 4; ++reg) {
                int gr = n0 + wm * 64 + mr * 16 + kg * 4 + reg;
                if (gr >= N) continue;
                int gc = cb * 64 + wn * 16 + r15;
                y[(size_t)gr * YW + gc] = f2bf(acc[mr][reg]);
            }
        }
        __syncthreads();
    }
}

// ---------------------------------------------------------------------------
// 5. gather: out[n] = relu( sum_e w_e * y[(pv+(pv>>3))*128..] + y_root + bias )
//    Boundaries from pad_offs[n*8], pad_offs[n*8+8]; weights from hist.
// ---------------------------------------------------------------------------
__global__ __launch_bounds__(256) void gather_kernel(
    const unsigned short* __restrict__ y,
    const int* __restrict__ perm,
    const int* __restrict__ pad_offs,
    const int* __restrict__ hist,
    const float* __restrict__ bias,
    float* __restrict__ out, int N)
{
    int wid  = threadIdx.x >> 6;
    int lane = threadIdx.x & 63;
    int n    = blockIdx.x * 4 + wid;
    if (n >= N) return;

    int beg = pad_offs[n * NREL];
    int end = pad_offs[n * NREL + NREL];

    int4 h0 = *(const int4*)(hist + (size_t)n * NREL);
    int4 h1 = *(const int4*)(hist + (size_t)n * NREL + 4);
    float iw0 = 1.0f / (float)max(h0.x, 1);
    float iw1 = 1.0f / (float)max(h0.y, 1);
    float iw2 = 1.0f / (float)max(h0.z, 1);
    float iw3 = 1.0f / (float)max(h0.w, 1);
    float iw4 = 1.0f / (float)max(h1.x, 1);
    float iw5 = 1.0f / (float)max(h1.y, 1);
    float iw6 = 1.0f / (float)max(h1.z, 1);
    float iw7 = 1.0f / (float)max(h1.w, 1);

    const unsigned* y32 = (const unsigned*)y;
    float a0 = 0.f, a1 = 0.f;

    for (int blk = beg; blk < end; blk += 64) {
        int m = end - blk; if (m > 64) m = 64;
        int   rv = 0;
        float wv = 0.f;
        if (lane < m) {
            int pv  = perm[blk + lane];
            int rel = pv & 7;
            rv = pv + (pv >> 3);                  // = src*9 + rel
            float wa = (rel & 1) ? iw1 : iw0;
            float wb = (rel & 1) ? iw3 : iw2;
            float wc = (rel & 1) ? iw5 : iw4;
            float wd = (rel & 1) ? iw7 : iw6;
            float we_ = (rel & 2) ? wb : wa;
            float wf  = (rel & 2) ? wd : wc;
            wv = (rel & 4) ? wf : we_;
        }

        int j = 0;
#define EDGE_LOAD(K) \
            int   p##K = __shfl(rv, j + K);                     \
            float w##K = __shfl(wv, j + K);                     \
            unsigned u##K = y32[(size_t)p##K * 64 + lane];
#define EDGE_ACC(K) \
            a0 += w##K * lof(u##K); a1 += w##K * hif(u##K);

        for (; j + 16 <= m; j += 16) {
            EDGE_LOAD(0) EDGE_LOAD(1) EDGE_LOAD(2)  EDGE_LOAD(3)
            EDGE_LOAD(4) EDGE_LOAD(5) EDGE_LOAD(6)  EDGE_LOAD(7)
            EDGE_LOAD(8) EDGE_LOAD(9) EDGE_LOAD(10) EDGE_LOAD(11)
            EDGE_LOAD(12) EDGE_LOAD(13) EDGE_LOAD(14) EDGE_LOAD(15)
            EDGE_ACC(0)  EDGE_ACC(1)  EDGE_ACC(2)  EDGE_ACC(3)
            EDGE_ACC(4)  EDGE_ACC(5)  EDGE_ACC(6)  EDGE_ACC(7)
            EDGE_ACC(8)  EDGE_ACC(9)  EDGE_ACC(10) EDGE_ACC(11)
            EDGE_ACC(12) EDGE_ACC(13) EDGE_ACC(14) EDGE_ACC(15)
        }
        if (j + 8 <= m) {
            EDGE_LOAD(0) EDGE_LOAD(1) EDGE_LOAD(2) EDGE_LOAD(3)
            EDGE_LOAD(4) EDGE_LOAD(5) EDGE_LOAD(6) EDGE_LOAD(7)
            EDGE_ACC(0) EDGE_ACC(1) EDGE_ACC(2) EDGE_ACC(3)
            EDGE_ACC(4) EDGE_ACC(5) EDGE_ACC(6) EDGE_ACC(7)
            j += 8;
        }
        if (j + 4 <= m) {
            EDGE_LOAD(0) EDGE_LOAD(1) EDGE_LOAD(2) EDGE_LOAD(3)
            EDGE_ACC(0) EDGE_ACC(1) EDGE_ACC(2) EDGE_ACC(3)
            j += 4;
        }
        for (; j < m; ++j) {
            EDGE_LOAD(0)
            EDGE_ACC(0)
        }
#undef EDGE_LOAD
#undef EDGE_ACC
    }

    // root + bias + relu
    unsigned ur = y32[(size_t)n * YWD + (NREL * CH / 2) + lane];
    float o0 = a0 + lof(ur) + bias[lane * 2];
    float o1 = a1 + hif(ur) + bias[lane * 2 + 1];
    float2 ov;
    ov.x = fmaxf(o0, 0.f);
    ov.y = fmaxf(o1, 0.f);
    *(float2*)(out + (size_t)n * CH + lane * 2) = ov;
}

extern "C" void kernel_launch(void* const* d_in, const int* in_sizes, int n_in,
                              void* d_out, int out_size, void* d_ws, size_t ws_size,
                              hipStream_t stream)
{
    const float* x    = (const float*)d_in[0];
    const int*   ei   = (const int*)d_in[1];
    const int*   et   = (const int*)d_in[2];
    const float* W    = (const float*)d_in[3];
    const float* root = (const float*)d_in[4];
    const float* bias = (const float*)d_in[5];
    float*       out  = (float*)d_out;

    int N = in_sizes[0] / CH;
    int E = in_sizes[2];
    const int* src = ei;
    const int* dst = ei + E;

    int S  = N * NREL;
    int NB = (S + SCAN_CHUNK - 1) / SCAN_CHUNK;

    // workspace layout (~250 MB)
    unsigned short* y   = (unsigned short*)d_ws;              // N*1152 bf16
    unsigned short* Bt2 = y + (size_t)N * YW;                 // 1152*128 bf16
    int* hist     = (int*)(Bt2 + (size_t)YW * CH);            // S (persists)
    int* pad_offs = hist + S;                                 // S+1 (read-only post-finalize)
    int* partials = pad_offs + S + 1;                         // 256
    int* perm     = partials + 256;                           // E
    int* rank     = perm + E;                                 // E

    hipMemsetAsync(hist, 0, (size_t)S * sizeof(int), stream);

    int egrid = (E + 255) / 256;
    int G     = (N + 127) / 128;                              // ygemm grid
    int epb   = ((E + G - 1) / G + 2047) & ~2047;             // edges per block

    bt2_kernel<<<(YW * CH + 255) / 256, 256, 0, stream>>>(W, root, Bt2);
    hist_rank_kernel<<<egrid, 256, 0, stream>>>(dst, et, hist, rank, E);
    scan1_kernel<<<NB, SCAN_THREADS, 0, stream>>>(hist, pad_offs, partials, S);
    scan2_kernel<<<1, SCAN_THREADS, 0, stream>>>(partials, NB);
    finalize_kernel<<<(S + 256) / 256, 256, 0, stream>>>(pad_offs, partials, S, E);
    ygemm_fill_kernel<<<G, 512, 0, stream>>>(x, Bt2, y, N,
                                             src, dst, et, rank, pad_offs,
                                             perm, E, epb);
    gather_kernel<<<(N + 3) / 4, 256, 0, stream>>>(y, perm, pad_offs, hist, bias, out, N);
}